// Round 1
// baseline (659.813 us; speedup 1.0000x reference)
//
#include <hip/hip_runtime.h>
#include <hip/hip_bf16.h>
#include <stdint.h>
#include <math.h>

#define DEV static __device__ __forceinline__

typedef short bf16x8 __attribute__((ext_vector_type(8)));
typedef float f32x4 __attribute__((ext_vector_type(4)));
typedef unsigned short u16;

static constexpr int Sq   = 1024;  // sequence length
static constexpr int Dm   = 1024;  // model dim
static constexpr int Hh   = 16;    // heads
static constexpr int DKk  = 64;    // head dim
static constexpr int Mrows = 4096; // B*S
static constexpr int DFFn = 4096;

// ---------- helpers ----------

DEV u16 f2bf(float f) {  // fp32 -> bf16 (RNE)
    union { float f; unsigned u; } c; c.f = f;
    unsigned u = c.u;
    return (u16)((u + 0x7FFFu + ((u >> 16) & 1u)) >> 16);
}

DEV void gload_lds16(void* lds, const void* g) {
    // async global->LDS, 16B per lane; LDS dest = wave-uniform base + lane*16
    using gvp = __attribute__((address_space(1))) void*;
    using lvp = __attribute__((address_space(3))) void*;
    __builtin_amdgcn_global_load_lds((gvp)const_cast<void*>(g), (lvp)lds, 16, 0, 0);
}

// ---------- fp32 -> bf16 cast ----------

__global__ __launch_bounds__(256) void cast_bf16_kernel(
    const float* __restrict__ in, u16* __restrict__ out, int n4)
{
    int i = blockIdx.x * 256 + threadIdx.x;
    if (i >= n4) return;
    float4 v = ((const float4*)in)[i];
    ushort4 o;
    o.x = f2bf(v.x); o.y = f2bf(v.y); o.z = f2bf(v.z); o.w = f2bf(v.w);
    ((ushort4*)out)[i] = o;
}

// ---------- GEMM: C[M,N] = A[M,K] * W[N,K]^T + bias ----------
// m97 structure: 128x128 tile, BK=32, 4 waves (2x2) of 64x64, 16x16x32 bf16 MFMA.

template<int OUT_BF16, int RELU>
__global__ __launch_bounds__(256) void gemm_bt_kernel(
    const u16* __restrict__ A, const u16* __restrict__ W,
    const float* __restrict__ bias, void* __restrict__ Cout,
    int N, int K)
{
    __shared__ u16 Ald[128 * 32];
    __shared__ u16 Bld[128 * 32];
    const int tid = threadIdx.x;
    const int w  = tid >> 6, l = tid & 63;
    const int lr = l & 15,  lg = l >> 4;
    const int wr = w >> 1,  wc = w & 1;
    const size_t tm = (size_t)blockIdx.y * 128;
    const size_t tn = (size_t)blockIdx.x * 128;

    // staging: thread t covers row tm + t/4 (and +64), cols (t%4)*8..+7 of the K-slice
    const u16* Asrc = A + (tm + (size_t)(tid >> 2)) * (size_t)K + (size_t)(tid & 3) * 8;
    const u16* Bsrc = W + (tn + (size_t)(tid >> 2)) * (size_t)K + (size_t)(tid & 3) * 8;
    u16* AldW = Ald + w * 512;   // wave-uniform LDS base (lane*16B appended by HW)
    u16* BldW = Bld + w * 512;

    f32x4 acc[4][4] = {};

    for (int k0 = 0; k0 < K; k0 += 32) {
        __syncthreads();                       // prev compute done before overwrite
        gload_lds16(AldW,        Asrc + k0);
        gload_lds16(AldW + 2048, Asrc + (size_t)64 * K + k0);
        gload_lds16(BldW,        Bsrc + k0);
        gload_lds16(BldW + 2048, Bsrc + (size_t)64 * K + k0);
        __syncthreads();                       // drains vmcnt -> tiles visible

        bf16x8 af[4], bfv[4];
        #pragma unroll
        for (int m = 0; m < 4; ++m)
            af[m] = *(const bf16x8*)&Ald[(wr * 64 + m * 16 + lr) * 32 + lg * 8];
        #pragma unroll
        for (int n = 0; n < 4; ++n)
            bfv[n] = *(const bf16x8*)&Bld[(wc * 64 + n * 16 + lr) * 32 + lg * 8];
        #pragma unroll
        for (int m = 0; m < 4; ++m)
            #pragma unroll
            for (int n = 0; n < 4; ++n)
                acc[m][n] = __builtin_amdgcn_mfma_f32_16x16x32_bf16(af[m], bfv[n], acc[m][n], 0, 0, 0);
    }

    float bv[4];
    #pragma unroll
    for (int n = 0; n < 4; ++n) bv[n] = bias[tn + wc * 64 + n * 16 + lr];

    #pragma unroll
    for (int m = 0; m < 4; ++m) {
        #pragma unroll
        for (int n = 0; n < 4; ++n) {
            const size_t col = tn + wc * 64 + n * 16 + lr;
            #pragma unroll
            for (int j = 0; j < 4; ++j) {
                const size_t row = tm + wr * 64 + m * 16 + lg * 4 + j;  // C/D: row=(l>>4)*4+j, col=l&15
                float v = acc[m][n][j] + bv[n];
                if (RELU) v = fmaxf(v, 0.f);
                if (OUT_BF16) ((u16*)Cout)[row * (size_t)N + col] = f2bf(v);
                else          ((float*)Cout)[row * (size_t)N + col] = v;
            }
        }
    }
}

// ---------- flash attention (bf16 MFMA, online softmax) ----------
// grid: (S/64, B*H); block 256 = 4 waves; wave w owns q-rows q0+w*16..+15.
// Q/K/V/O are (B*S, D) bf16, head h occupies cols h*64..h*64+63.

template<int CAUSAL>
__global__ __launch_bounds__(256) void attn_kernel(
    const u16* __restrict__ Qm, const u16* __restrict__ Km,
    const u16* __restrict__ Vm, u16* __restrict__ Om)
{
    __shared__ u16 Kld[32 * 64];      // [key][dk]
    __shared__ u16 Vtd[64 * 32];      // [dk][key]  (transposed for b128 B-frags)
    __shared__ u16 Pld[4][16 * 32];   // per-wave P tile

    const int tid = threadIdx.x;
    const int w = tid >> 6, l = tid & 63;
    const int lr = l & 15, lg = l >> 4;
    const int bh = blockIdx.y;
    const int b = bh >> 4, h = bh & 15;
    const int q0 = blockIdx.x * 64;
    const size_t base = ((size_t)b * Sq) * Dm + (size_t)h * DKk;

    // Q fragments for this wave's 16 rows (A-frag: row=l&15, k=(l>>4)*8+i)
    const int qrow = q0 + w * 16 + lr;
    const bf16x8 aq0 = *(const bf16x8*)&Qm[base + (size_t)qrow * Dm + lg * 8];
    const bf16x8 aq1 = *(const bf16x8*)&Qm[base + (size_t)qrow * Dm + 32 + lg * 8];

    f32x4 o[4] = {};
    float mj[4] = { -INFINITY, -INFINITY, -INFINITY, -INFINITY };
    float lj[4] = {};

    const int srow = tid >> 3;           // staging: 32 rows x 64 cols, 16B/thread
    const int scol = (tid & 7) * 8;
    const int kv_end = CAUSAL ? (q0 + 64) : Sq;

    for (int kv0 = 0; kv0 < kv_end; kv0 += 32) {
        __syncthreads();
        {
            uint4 kvec = *(const uint4*)&Km[base + (size_t)(kv0 + srow) * Dm + scol];
            *(uint4*)&Kld[srow * 64 + scol] = kvec;
            uint4 vvec = *(const uint4*)&Vm[base + (size_t)(kv0 + srow) * Dm + scol];
            const u16* vsp = (const u16*)&vvec;
            #pragma unroll
            for (int i = 0; i < 8; ++i) Vtd[(scol + i) * 32 + srow] = vsp[i];
        }
        __syncthreads();

        // scores = Q(16x64) @ K_tile(32x64)^T  -> two 16x16 C-frags
        f32x4 s[2] = {};
        #pragma unroll
        for (int n = 0; n < 2; ++n) {
            bf16x8 kf0 = *(const bf16x8*)&Kld[(n * 16 + lr) * 64 + lg * 8];
            bf16x8 kf1 = *(const bf16x8*)&Kld[(n * 16 + lr) * 64 + 32 + lg * 8];
            s[n] = __builtin_amdgcn_mfma_f32_16x16x32_bf16(aq0, kf0, s[n], 0, 0, 0);
            s[n] = __builtin_amdgcn_mfma_f32_16x16x32_bf16(aq1, kf1, s[n], 0, 0, 0);
        }

        float sc[2][4];
        #pragma unroll
        for (int n = 0; n < 2; ++n) {
            #pragma unroll
            for (int j = 0; j < 4; ++j) {
                float v = s[n][j] * 0.125f;   // 1/sqrt(64)
                if (CAUSAL) {
                    int key = kv0 + n * 16 + lr;
                    int row = q0 + w * 16 + lg * 4 + j;
                    if (key > row) v = -1e9f;
                }
                sc[n][j] = v;
            }
        }

        // online softmax; row r=(lg*4+j) values live in the 16 lanes sharing lg
        float scale[4], p0[4], p1[4];
        #pragma unroll
        for (int j = 0; j < 4; ++j) {
            float t = fmaxf(sc[0][j], sc[1][j]);
            t = fmaxf(t, __shfl_xor(t, 1));
            t = fmaxf(t, __shfl_xor(t, 2));
            t = fmaxf(t, __shfl_xor(t, 4));
            t = fmaxf(t, __shfl_xor(t, 8));
            float nm = fmaxf(mj[j], t);
            scale[j] = __expf(mj[j] - nm);
            p0[j] = __expf(sc[0][j] - nm);
            p1[j] = __expf(sc[1][j] - nm);
            float rs = p0[j] + p1[j];
            rs += __shfl_xor(rs, 1);
            rs += __shfl_xor(rs, 2);
            rs += __shfl_xor(rs, 4);
            rs += __shfl_xor(rs, 8);
            lj[j] = lj[j] * scale[j] + rs;
            mj[j] = nm;
        }
        #pragma unroll
        for (int n2 = 0; n2 < 4; ++n2)
            #pragma unroll
            for (int j = 0; j < 4; ++j) o[n2][j] *= scale[j];

        // P -> LDS (bf16), then re-read as MFMA A-frag (same-wave DS ops are in-order)
        #pragma unroll
        for (int j = 0; j < 4; ++j) {
            Pld[w][(lg * 4 + j) * 32 + lr]      = f2bf(p0[j]);
            Pld[w][(lg * 4 + j) * 32 + 16 + lr] = f2bf(p1[j]);
        }
        bf16x8 pa = *(const bf16x8*)&Pld[w][lr * 32 + lg * 8];
        #pragma unroll
        for (int n2 = 0; n2 < 4; ++n2) {
            bf16x8 vf = *(const bf16x8*)&Vtd[(n2 * 16 + lr) * 32 + lg * 8];
            o[n2] = __builtin_amdgcn_mfma_f32_16x16x32_bf16(pa, vf, o[n2], 0, 0, 0);
        }
    }

    #pragma unroll
    for (int n2 = 0; n2 < 4; ++n2) {
        #pragma unroll
        for (int j = 0; j < 4; ++j) {
            const size_t row = (size_t)q0 + w * 16 + lg * 4 + j;
            float v = o[n2][j] / lj[j];
            Om[base + row * Dm + n2 * 16 + lr] = f2bf(v);
        }
    }
}

// ---------- add + LayerNorm ----------
// y = LN(a+b)*g+beta; one block per row (D=1024), 256 threads x float4

__global__ __launch_bounds__(256) void add_ln_kernel(
    const float* __restrict__ A, const float* __restrict__ Bv,
    const float* __restrict__ g, const float* __restrict__ be,
    float* __restrict__ Y, u16* __restrict__ Ybf)
{
    const int row = blockIdx.x;
    const int tid = threadIdx.x;
    const size_t off = (size_t)row * Dm;
    float4 a4 = ((const float4*)(A + off))[tid];
    float4 b4 = ((const float4*)(Bv + off))[tid];
    float4 xv;
    xv.x = a4.x + b4.x; xv.y = a4.y + b4.y; xv.z = a4.z + b4.z; xv.w = a4.w + b4.w;
    float s = xv.x + xv.y + xv.z + xv.w;
    float q = xv.x * xv.x + xv.y * xv.y + xv.z * xv.z + xv.w * xv.w;
    #pragma unroll
    for (int m = 1; m < 64; m <<= 1) {
        s += __shfl_xor(s, m);
        q += __shfl_xor(q, m);
    }
    __shared__ float ss[4], qq[4];
    if ((tid & 63) == 0) { ss[tid >> 6] = s; qq[tid >> 6] = q; }
    __syncthreads();
    s = ss[0] + ss[1] + ss[2] + ss[3];
    q = qq[0] + qq[1] + qq[2] + qq[3];
    const float mean = s * (1.f / 1024.f);
    const float var  = q * (1.f / 1024.f) - mean * mean;
    const float rstd = rsqrtf(var + 1e-5f);
    float4 g4  = ((const float4*)g)[tid];
    float4 be4 = ((const float4*)be)[tid];
    float4 y;
    y.x = (xv.x - mean) * rstd * g4.x + be4.x;
    y.y = (xv.y - mean) * rstd * g4.y + be4.y;
    y.z = (xv.z - mean) * rstd * g4.z + be4.z;
    y.w = (xv.w - mean) * rstd * g4.w + be4.w;
    ((float4*)(Y + off))[tid] = y;
    if (Ybf) {
        ushort4 ob;
        ob.x = f2bf(y.x); ob.y = f2bf(y.y); ob.z = f2bf(y.z); ob.w = f2bf(y.w);
        ((ushort4*)(Ybf + off))[tid] = ob;
    }
}

// ---------- launch ----------

extern "C" void kernel_launch(void* const* d_in, const int* in_sizes, int n_in,
                              void* d_out, int out_size, void* d_ws, size_t ws_size,
                              hipStream_t stream)
{
    const float* x       = (const float*)d_in[0];
    const float* enc     = (const float*)d_in[1];
    // d_in[2] source_mask (unused: cross-attn has no mask), d_in[3] target_mask (tril -> causal hard-coded)
    const float* sa_wq   = (const float*)d_in[4];
    const float* sa_bq   = (const float*)d_in[5];
    const float* sa_wk   = (const float*)d_in[6];
    const float* sa_bk   = (const float*)d_in[7];
    const float* sa_wv   = (const float*)d_in[8];
    const float* sa_bv   = (const float*)d_in[9];
    const float* sa_wo   = (const float*)d_in[10];
    const float* sa_bo   = (const float*)d_in[11];
    const float* ca_in_w = (const float*)d_in[12];
    const float* ca_in_b = (const float*)d_in[13];
    const float* ca_out_w= (const float*)d_in[14];
    const float* ca_out_b= (const float*)d_in[15];
    const float* ff_w1   = (const float*)d_in[16];
    const float* ff_b1   = (const float*)d_in[17];
    const float* ff_w2   = (const float*)d_in[18];
    const float* ff_b2   = (const float*)d_in[19];
    const float* n1_g = (const float*)d_in[20];
    const float* n1_b = (const float*)d_in[21];
    const float* n2_g = (const float*)d_in[22];
    const float* n2_b = (const float*)d_in[23];
    const float* n3_g = (const float*)d_in[24];
    const float* n3_b = (const float*)d_in[25];

    char* p = (char*)d_ws;
    auto take = [&](size_t bytes) -> char* {
        char* r = p; p += (bytes + 255) & ~(size_t)255; return r;
    };
    const size_t MDbf = (size_t)Mrows * Dm * 2;
    const size_t MDf  = (size_t)Mrows * Dm * 4;

    u16* xb     = (u16*)take(MDbf);
    u16* encb   = (u16*)take(MDbf);
    u16* wqb    = (u16*)take((size_t)Dm * Dm * 2);
    u16* wkb    = (u16*)take((size_t)Dm * Dm * 2);
    u16* wvb    = (u16*)take((size_t)Dm * Dm * 2);
    u16* wob    = (u16*)take((size_t)Dm * Dm * 2);
    u16* cainb  = (u16*)take((size_t)3 * Dm * Dm * 2);
    u16* caoutb = (u16*)take((size_t)Dm * Dm * 2);
    u16* fw1b   = (u16*)take((size_t)DFFn * Dm * 2);
    u16* fw2b   = (u16*)take((size_t)Dm * DFFn * 2);
    u16* Qb     = (u16*)take(MDbf);
    u16* Kb     = (u16*)take(MDbf);
    u16* Vb     = (u16*)take(MDbf);
    u16* AOb    = (u16*)take(MDbf);
    float* tmpf = (float*)take(MDf);
    float* x1f  = (float*)take(MDf);
    u16*   x1b  = (u16*)take(MDbf);
    float* x2f  = (float*)take(MDf);
    u16*   x2b  = (u16*)take(MDbf);
    u16* ffh = Qb;  // FF hidden (4096x4096 bf16, 32MB) aliases dead Qb..AOb span (33.5MB)
    if ((size_t)(p - (char*)d_ws) > ws_size) return;  // loud failure instead of corruption

    auto cast = [&](const float* src, u16* dst, size_t n) {
        int n4 = (int)(n / 4);
        cast_bf16_kernel<<<dim3((n4 + 255) / 256), dim3(256), 0, stream>>>(src, dst, n4);
    };
    cast(x, xb, (size_t)Mrows * Dm);
    cast(enc, encb, (size_t)Mrows * Dm);
    cast(sa_wq, wqb, (size_t)Dm * Dm);
    cast(sa_wk, wkb, (size_t)Dm * Dm);
    cast(sa_wv, wvb, (size_t)Dm * Dm);
    cast(sa_wo, wob, (size_t)Dm * Dm);
    cast(ca_in_w, cainb, (size_t)3 * Dm * Dm);
    cast(ca_out_w, caoutb, (size_t)Dm * Dm);
    cast(ff_w1, fw1b, (size_t)DFFn * Dm);
    cast(ff_w2, fw2b, (size_t)Dm * DFFn);

    const dim3 blk(256);
    auto gemm_b = [&](const u16* A, const u16* W, const float* bias, u16* C, int N, int K) {
        gemm_bt_kernel<1, 0><<<dim3(N / 128, Mrows / 128), blk, 0, stream>>>(A, W, bias, (void*)C, N, K);
    };

    // ---- self-attention block ----
    gemm_b(xb, wqb, sa_bq, Qb, Dm, Dm);
    gemm_b(xb, wkb, sa_bk, Kb, Dm, Dm);
    gemm_b(xb, wvb, sa_bv, Vb, Dm, Dm);
    attn_kernel<1><<<dim3(Sq / 64, 4 * Hh), blk, 0, stream>>>(Qb, Kb, Vb, AOb);
    gemm_bt_kernel<0, 0><<<dim3(Dm / 128, Mrows / 128), blk, 0, stream>>>(AOb, wob, sa_bo, (void*)tmpf, Dm, Dm);
    add_ln_kernel<<<dim3(Mrows), blk, 0, stream>>>(x, tmpf, n1_g, n1_b, x1f, x1b);

    // ---- cross-attention block ----
    gemm_b(x1b,  cainb,                       ca_in_b,          Qb, Dm, Dm);
    gemm_b(encb, cainb + (size_t)Dm * Dm,     ca_in_b + Dm,     Kb, Dm, Dm);
    gemm_b(encb, cainb + (size_t)2 * Dm * Dm, ca_in_b + 2 * Dm, Vb, Dm, Dm);
    attn_kernel<0><<<dim3(Sq / 64, 4 * Hh), blk, 0, stream>>>(Qb, Kb, Vb, AOb);
    gemm_bt_kernel<0, 0><<<dim3(Dm / 128, Mrows / 128), blk, 0, stream>>>(AOb, caoutb, ca_out_b, (void*)tmpf, Dm, Dm);
    add_ln_kernel<<<dim3(Mrows), blk, 0, stream>>>(x1f, tmpf, n2_g, n2_b, x2f, x2b);

    // ---- feed-forward block ----
    gemm_bt_kernel<1, 1><<<dim3(DFFn / 128, Mrows / 128), blk, 0, stream>>>(x2b, fw1b, ff_b1, (void*)ffh, DFFn, Dm);
    gemm_bt_kernel<0, 0><<<dim3(Dm / 128, Mrows / 128), blk, 0, stream>>>(ffh, fw2b, ff_b2, (void*)tmpf, Dm, DFFn);
    add_ln_kernel<<<dim3(Mrows), blk, 0, stream>>>(x2f, tmpf, n3_g, n3_b, (float*)d_out, nullptr);
}

// Round 2
// 471.978 us; speedup vs baseline: 1.3980x; 1.3980x over previous
//
#include <hip/hip_runtime.h>
#include <hip/hip_bf16.h>
#include <stdint.h>
#include <math.h>

#define DEV static __device__ __forceinline__

typedef short bf16x8 __attribute__((ext_vector_type(8)));
typedef float f32x4 __attribute__((ext_vector_type(4)));
typedef unsigned short u16;

static constexpr int Sq   = 1024;
static constexpr int Dm   = 1024;
static constexpr int Hh   = 16;
static constexpr int Mrows = 4096; // B*S
static constexpr int DFFn = 4096;

// ---------- helpers ----------

DEV u16 f2bf(float f) {  // fp32 -> bf16 (RNE)
    union { float f; unsigned u; } c; c.f = f;
    unsigned u = c.u;
    return (u16)((u + 0x7FFFu + ((u >> 16) & 1u)) >> 16);
}

DEV void gload_lds16(void* lds, const void* g) {
    using gvp = __attribute__((address_space(1))) void*;
    using lvp = __attribute__((address_space(3))) void*;
    __builtin_amdgcn_global_load_lds((gvp)const_cast<void*>(g), (lvp)lds, 16, 0, 0);
}

// ---------- fp32 -> bf16 cast ----------

__global__ __launch_bounds__(256) void cast_bf16_kernel(
    const float* __restrict__ in, u16* __restrict__ out, int n4)
{
    int i = blockIdx.x * 256 + threadIdx.x;
    if (i >= n4) return;
    float4 v = ((const float4*)in)[i];
    ushort4 o;
    o.x = f2bf(v.x); o.y = f2bf(v.y); o.z = f2bf(v.z); o.w = f2bf(v.w);
    ((ushort4*)out)[i] = o;
}

// ---------- GEMM 128x128 (m97 structure): C[M,N] = A[M,K] * W[N,K]^T + bias ----------

template<int OUT_BF16, int RELU>
__global__ __launch_bounds__(256) void gemm_bt_kernel(
    const u16* __restrict__ A, const u16* __restrict__ W,
    const float* __restrict__ bias, void* __restrict__ Cout,
    int N, int K)
{
    __shared__ u16 Ald[128 * 32];
    __shared__ u16 Bld[128 * 32];
    const int tid = threadIdx.x;
    const int w  = tid >> 6, l = tid & 63;
    const int lr = l & 15,  lg = l >> 4;
    const int wr = w >> 1,  wc = w & 1;
    const size_t tm = (size_t)blockIdx.y * 128;
    const size_t tn = (size_t)blockIdx.x * 128;

    const u16* Asrc = A + (tm + (size_t)(tid >> 2)) * (size_t)K + (size_t)(tid & 3) * 8;
    const u16* Bsrc = W + (tn + (size_t)(tid >> 2)) * (size_t)K + (size_t)(tid & 3) * 8;
    u16* AldW = Ald + w * 512;
    u16* BldW = Bld + w * 512;

    f32x4 acc[4][4] = {};

    for (int k0 = 0; k0 < K; k0 += 32) {
        __syncthreads();
        gload_lds16(AldW,        Asrc + k0);
        gload_lds16(AldW + 2048, Asrc + (size_t)64 * K + k0);
        gload_lds16(BldW,        Bsrc + k0);
        gload_lds16(BldW + 2048, Bsrc + (size_t)64 * K + k0);
        __syncthreads();

        bf16x8 af[4], bfv[4];
        #pragma unroll
        for (int m = 0; m < 4; ++m)
            af[m] = *(const bf16x8*)&Ald[(wr * 64 + m * 16 + lr) * 32 + lg * 8];
        #pragma unroll
        for (int n = 0; n < 4; ++n)
            bfv[n] = *(const bf16x8*)&Bld[(wc * 64 + n * 16 + lr) * 32 + lg * 8];
        #pragma unroll
        for (int m = 0; m < 4; ++m)
            #pragma unroll
            for (int n = 0; n < 4; ++n)
                acc[m][n] = __builtin_amdgcn_mfma_f32_16x16x32_bf16(af[m], bfv[n], acc[m][n], 0, 0, 0);
    }

    float bv[4];
    #pragma unroll
    for (int n = 0; n < 4; ++n) bv[n] = bias[tn + wc * 64 + n * 16 + lr];

    #pragma unroll
    for (int m = 0; m < 4; ++m) {
        #pragma unroll
        for (int n = 0; n < 4; ++n) {
            const size_t col = tn + wc * 64 + n * 16 + lr;
            #pragma unroll
            for (int j = 0; j < 4; ++j) {
                const size_t row = tm + wr * 64 + m * 16 + lg * 4 + j;
                float v = acc[m][n][j] + bv[n];
                if (RELU) v = fmaxf(v, 0.f);
                if (OUT_BF16) ((u16*)Cout)[row * (size_t)N + col] = f2bf(v);
                else          ((float*)Cout)[row * (size_t)N + col] = v;
            }
        }
    }
}

// ---------- GEMM 64x128 variant (2 blocks/CU for N=1024 shapes) ----------
// 4 waves in a row; wave w computes 64 x 32 at col offset w*32.

template<int OUT_BF16, int RELU>
__global__ __launch_bounds__(256) void gemm_bt64_kernel(
    const u16* __restrict__ A, const u16* __restrict__ W,
    const float* __restrict__ bias, void* __restrict__ Cout,
    int N, int K)
{
    __shared__ u16 Ald[64 * 32];
    __shared__ u16 Bld[128 * 32];
    const int tid = threadIdx.x;
    const int w  = tid >> 6, l = tid & 63;
    const int lr = l & 15,  lg = l >> 4;
    const size_t tm = (size_t)blockIdx.y * 64;
    const size_t tn = (size_t)blockIdx.x * 128;

    const u16* Asrc = A + (tm + (size_t)(tid >> 2)) * (size_t)K + (size_t)(tid & 3) * 8;
    const u16* Bsrc = W + (tn + (size_t)(tid >> 2)) * (size_t)K + (size_t)(tid & 3) * 8;
    u16* AldW = Ald + w * 512;
    u16* BldW = Bld + w * 512;

    f32x4 acc[4][2] = {};

    for (int k0 = 0; k0 < K; k0 += 32) {
        __syncthreads();
        gload_lds16(AldW,        Asrc + k0);
        gload_lds16(BldW,        Bsrc + k0);
        gload_lds16(BldW + 2048, Bsrc + (size_t)64 * K + k0);
        __syncthreads();

        bf16x8 af[4], bfv[2];
        #pragma unroll
        for (int m = 0; m < 4; ++m)
            af[m] = *(const bf16x8*)&Ald[(m * 16 + lr) * 32 + lg * 8];
        #pragma unroll
        for (int n = 0; n < 2; ++n)
            bfv[n] = *(const bf16x8*)&Bld[(w * 32 + n * 16 + lr) * 32 + lg * 8];
        #pragma unroll
        for (int m = 0; m < 4; ++m)
            #pragma unroll
            for (int n = 0; n < 2; ++n)
                acc[m][n] = __builtin_amdgcn_mfma_f32_16x16x32_bf16(af[m], bfv[n], acc[m][n], 0, 0, 0);
    }

    float bv[2];
    #pragma unroll
    for (int n = 0; n < 2; ++n) bv[n] = bias[tn + w * 32 + n * 16 + lr];

    #pragma unroll
    for (int m = 0; m < 4; ++m) {
        #pragma unroll
        for (int n = 0; n < 2; ++n) {
            const size_t col = tn + w * 32 + n * 16 + lr;
            #pragma unroll
            for (int j = 0; j < 4; ++j) {
                const size_t row = tm + m * 16 + lg * 4 + j;
                float v = acc[m][n][j] + bv[n];
                if (RELU) v = fmaxf(v, 0.f);
                if (OUT_BF16) ((u16*)Cout)[row * (size_t)N + col] = f2bf(v);
                else          ((float*)Cout)[row * (size_t)N + col] = v;
            }
        }
    }
}

// ---------- flash attention, KVBLK=64, XOR-swizzled LDS, double-buffered ----------
// grid: (S/64, B*H); block 256 = 4 waves; wave w owns q-rows q0+w*16..+15.
// All LDS tiles have 128B rows; swizzle: byte ^= (row&7)<<4 (bank-optimal b128 reads).

template<int CAUSAL>
__global__ __launch_bounds__(256) void attn_kernel(
    const u16* __restrict__ Qm, int ldq,
    const u16* __restrict__ Km, int ldk,
    const u16* __restrict__ Vm, int ldv,
    u16* __restrict__ Om)
{
    __shared__ u16 Kld[2][64 * 64];   // [key][dk], swizzled
    __shared__ u16 Vt [2][64 * 64];   // [dk][key], swizzled
    __shared__ u16 Pld[4][16 * 64];   // per-wave P, swizzled

    const int tid = threadIdx.x;
    const int w = tid >> 6, l = tid & 63;
    const int lr = l & 15, lg = l >> 4;
    const int bh = blockIdx.y;
    const int b = bh >> 4, h = bh & 15;
    const int q0 = blockIdx.x * 64;
    const size_t baseQ = (size_t)b * Sq * ldq + (size_t)h * 64;
    const size_t baseK = (size_t)b * Sq * ldk + (size_t)h * 64;
    const size_t baseV = (size_t)b * Sq * ldv + (size_t)h * 64;
    const size_t baseO = (size_t)b * Sq * Dm  + (size_t)h * 64;

    // Q fragments (A-frag: row=l&15, k=(l>>4)*8+i)
    const int qrow = q0 + w * 16 + lr;
    const bf16x8 aq0 = *(const bf16x8*)&Qm[baseQ + (size_t)qrow * ldq + lg * 8];
    const bf16x8 aq1 = *(const bf16x8*)&Qm[baseQ + (size_t)qrow * ldq + 32 + lg * 8];

    // staging thread map
    const int kr  = tid >> 2;          // K row 0..63
    const int kcB = (tid & 3) * 32;    // K col byte offset (32B group)
    const int vdg = tid >> 5;          // V d-group 0..7
    const int vkp = tid & 31;          // V k-pair 0..31

    f32x4 o[4] = {};
    float mj[4] = { -INFINITY, -INFINITY, -INFINITY, -INFINITY };
    float lj[4] = {};

    const int kv_end = CAUSAL ? (q0 + 64) : Sq;
    const int nt = kv_end >> 6;

    uint4 ka, kb, va, vb;
    auto loadKV = [&](int kv) {
        ka = *(const uint4*)&Km[baseK + (size_t)(kv + kr) * ldk + kcB / 2];
        kb = *(const uint4*)&Km[baseK + (size_t)(kv + kr) * ldk + kcB / 2 + 8];
        va = *(const uint4*)&Vm[baseV + (size_t)(kv + vkp * 2    ) * ldv + vdg * 8];
        vb = *(const uint4*)&Vm[baseV + (size_t)(kv + vkp * 2 + 1) * ldv + vdg * 8];
    };

    loadKV(0);

    for (int t = 0; t < nt; ++t) {
        const int bsel = t & 1;
        const int kv0 = t << 6;
        {   // stage regs -> LDS (swizzled)
            char* Kb_ = (char*)Kld[bsel];
            char* Vb_ = (char*)Vt[bsel];
            const int sk = (kr & 7) << 4;
            *(uint4*)(Kb_ + kr * 128 + ((kcB     ) ^ sk)) = ka;
            *(uint4*)(Kb_ + kr * 128 + ((kcB + 16) ^ sk)) = kb;
            const u16* pa_ = (const u16*)&va;
            const u16* pb_ = (const u16*)&vb;
            #pragma unroll
            for (int i = 0; i < 8; ++i) {
                const int d = vdg * 8 + i;
                unsigned val = (unsigned)pa_[i] | ((unsigned)pb_[i] << 16);
                *(unsigned*)(Vb_ + d * 128 + ((vkp * 4) ^ ((d & 7) << 4))) = val;
            }
        }
        __syncthreads();
        if (t + 1 < nt) loadKV((t + 1) << 6);   // overlap with compute below

        const char* Kb_ = (const char*)Kld[bsel];
        const char* Vb_ = (const char*)Vt[bsel];

        // QK^T: 16q x 64k
        f32x4 s[4] = {};
        #pragma unroll
        for (int n = 0; n < 4; ++n) {
            const int row = n * 16 + lr;
            const int sk = (row & 7) << 4;
            bf16x8 kf0 = *(const bf16x8*)(Kb_ + row * 128 + ((     lg * 16) ^ sk));
            bf16x8 kf1 = *(const bf16x8*)(Kb_ + row * 128 + ((64 + lg * 16) ^ sk));
            s[n] = __builtin_amdgcn_mfma_f32_16x16x32_bf16(aq0, kf0, s[n], 0, 0, 0);
            s[n] = __builtin_amdgcn_mfma_f32_16x16x32_bf16(aq1, kf1, s[n], 0, 0, 0);
        }

        float sc[4][4];
        const bool diag = CAUSAL && (kv0 == q0);
        #pragma unroll
        for (int n = 0; n < 4; ++n)
            #pragma unroll
            for (int j = 0; j < 4; ++j) {
                float v = s[n][j] * 0.125f;
                if (diag) {
                    int key = kv0 + n * 16 + lr;
                    int row = q0 + w * 16 + lg * 4 + j;
                    if (key > row) v = -1e9f;
                }
                sc[n][j] = v;
            }

        // online softmax over 64 keys (row r=lg*4+j lives in the 16 lanes sharing lg)
        float scl[4], p[4][4];
        #pragma unroll
        for (int j = 0; j < 4; ++j) {
            float t0 = fmaxf(fmaxf(sc[0][j], sc[1][j]), fmaxf(sc[2][j], sc[3][j]));
            t0 = fmaxf(t0, __shfl_xor(t0, 1));
            t0 = fmaxf(t0, __shfl_xor(t0, 2));
            t0 = fmaxf(t0, __shfl_xor(t0, 4));
            t0 = fmaxf(t0, __shfl_xor(t0, 8));
            float nm = fmaxf(mj[j], t0);
            scl[j] = __expf(mj[j] - nm);
            float rs = 0.f;
            #pragma unroll
            for (int n = 0; n < 4; ++n) { p[n][j] = __expf(sc[n][j] - nm); rs += p[n][j]; }
            rs += __shfl_xor(rs, 1);
            rs += __shfl_xor(rs, 2);
            rs += __shfl_xor(rs, 4);
            rs += __shfl_xor(rs, 8);
            lj[j] = lj[j] * scl[j] + rs;
            mj[j] = nm;
        }
        #pragma unroll
        for (int n2 = 0; n2 < 4; ++n2)
            #pragma unroll
            for (int j = 0; j < 4; ++j) o[n2][j] *= scl[j];

        // P -> LDS (swizzled), re-read as A-frag (same-wave DS in-order)
        char* Pw = (char*)Pld[w];
        #pragma unroll
        for (int j = 0; j < 4; ++j) {
            const int prow = lg * 4 + j;
            const int sk = (prow & 7) << 4;
            #pragma unroll
            for (int n = 0; n < 4; ++n)
                *(u16*)(Pw + prow * 128 + (((n * 16 + lr) * 2) ^ sk)) = f2bf(p[n][j]);
        }
        const int skp = (lr & 7) << 4;
        bf16x8 pa0 = *(const bf16x8*)(Pw + lr * 128 + ((     lg * 16) ^ skp));
        bf16x8 pa1 = *(const bf16x8*)(Pw + lr * 128 + ((64 + lg * 16) ^ skp));

        #pragma unroll
        for (int n2 = 0; n2 < 4; ++n2) {
            const int vrow = n2 * 16 + lr;
            const int sk = (vrow & 7) << 4;
            bf16x8 vf0 = *(const bf16x8*)(Vb_ + vrow * 128 + ((     lg * 16) ^ sk));
            bf16x8 vf1 = *(const bf16x8*)(Vb_ + vrow * 128 + ((64 + lg * 16) ^ sk));
            o[n2] = __builtin_amdgcn_mfma_f32_16x16x32_bf16(pa0, vf0, o[n2], 0, 0, 0);
            o[n2] = __builtin_amdgcn_mfma_f32_16x16x32_bf16(pa1, vf1, o[n2], 0, 0, 0);
        }
        __syncthreads();   // all reads of buf[bsel] done before next overwrite cycle
    }

    #pragma unroll
    for (int n2 = 0; n2 < 4; ++n2)
        #pragma unroll
        for (int j = 0; j < 4; ++j) {
            const size_t row = (size_t)q0 + w * 16 + lg * 4 + j;
            Om[baseO + row * Dm + n2 * 16 + lr] = f2bf(o[n2][j] / lj[j]);
        }
}

// ---------- add + LayerNorm ----------

__global__ __launch_bounds__(256) void add_ln_kernel(
    const float* __restrict__ A, const float* __restrict__ Bv,
    const float* __restrict__ g, const float* __restrict__ be,
    float* __restrict__ Y, u16* __restrict__ Ybf)
{
    const int row = blockIdx.x;
    const int tid = threadIdx.x;
    const size_t off = (size_t)row * Dm;
    float4 a4 = ((const float4*)(A + off))[tid];
    float4 b4 = ((const float4*)(Bv + off))[tid];
    float4 xv;
    xv.x = a4.x + b4.x; xv.y = a4.y + b4.y; xv.z = a4.z + b4.z; xv.w = a4.w + b4.w;
    float s = xv.x + xv.y + xv.z + xv.w;
    float q = xv.x * xv.x + xv.y * xv.y + xv.z * xv.z + xv.w * xv.w;
    #pragma unroll
    for (int m = 1; m < 64; m <<= 1) {
        s += __shfl_xor(s, m);
        q += __shfl_xor(q, m);
    }
    __shared__ float ss[4], qq[4];
    if ((tid & 63) == 0) { ss[tid >> 6] = s; qq[tid >> 6] = q; }
    __syncthreads();
    s = ss[0] + ss[1] + ss[2] + ss[3];
    q = qq[0] + qq[1] + qq[2] + qq[3];
    const float mean = s * (1.f / 1024.f);
    const float var  = q * (1.f / 1024.f) - mean * mean;
    const float rstd = rsqrtf(var + 1e-5f);
    float4 g4  = ((const float4*)g)[tid];
    float4 be4 = ((const float4*)be)[tid];
    float4 y;
    y.x = (xv.x - mean) * rstd * g4.x + be4.x;
    y.y = (xv.y - mean) * rstd * g4.y + be4.y;
    y.z = (xv.z - mean) * rstd * g4.z + be4.z;
    y.w = (xv.w - mean) * rstd * g4.w + be4.w;
    ((float4*)(Y + off))[tid] = y;
    if (Ybf) {
        ushort4 ob;
        ob.x = f2bf(y.x); ob.y = f2bf(y.y); ob.z = f2bf(y.z); ob.w = f2bf(y.w);
        ((ushort4*)(Ybf + off))[tid] = ob;
    }
}

// ---------- launch ----------

extern "C" void kernel_launch(void* const* d_in, const int* in_sizes, int n_in,
                              void* d_out, int out_size, void* d_ws, size_t ws_size,
                              hipStream_t stream)
{
    const float* x       = (const float*)d_in[0];
    const float* enc     = (const float*)d_in[1];
    const float* sa_wq   = (const float*)d_in[4];
    const float* sa_bq   = (const float*)d_in[5];
    const float* sa_wk   = (const float*)d_in[6];
    const float* sa_bk   = (const float*)d_in[7];
    const float* sa_wv   = (const float*)d_in[8];
    const float* sa_bv   = (const float*)d_in[9];
    const float* sa_wo   = (const float*)d_in[10];
    const float* sa_bo   = (const float*)d_in[11];
    const float* ca_in_w = (const float*)d_in[12];
    const float* ca_in_b = (const float*)d_in[13];
    const float* ca_out_w= (const float*)d_in[14];
    const float* ca_out_b= (const float*)d_in[15];
    const float* ff_w1   = (const float*)d_in[16];
    const float* ff_b1   = (const float*)d_in[17];
    const float* ff_w2   = (const float*)d_in[18];
    const float* ff_b2   = (const float*)d_in[19];
    const float* n1_g = (const float*)d_in[20];
    const float* n1_b = (const float*)d_in[21];
    const float* n2_g = (const float*)d_in[22];
    const float* n2_b = (const float*)d_in[23];
    const float* n3_g = (const float*)d_in[24];
    const float* n3_b = (const float*)d_in[25];

    char* p = (char*)d_ws;
    auto take = [&](size_t bytes) -> char* {
        char* r = p; p += (bytes + 255) & ~(size_t)255; return r;
    };
    const size_t MDbf = (size_t)Mrows * Dm * 2;
    const size_t MDf  = (size_t)Mrows * Dm * 4;
    const size_t DD   = (size_t)Dm * Dm;

    u16* xb     = (u16*)take(MDbf);
    u16* encb   = (u16*)take(MDbf);
    u16* wqkv   = (u16*)take(3 * DD * 2);   // fused self QKV weights [3072][1024]
    u16* wob    = (u16*)take(DD * 2);
    u16* cainb  = (u16*)take(3 * DD * 2);
    u16* caoutb = (u16*)take(DD * 2);
    u16* fw1b   = (u16*)take((size_t)DFFn * Dm * 2);
    u16* fw2b   = (u16*)take((size_t)Dm * DFFn * 2);
    float* bias3= (float*)take(3 * Dm * 4);
    u16* SCR    = (u16*)take((size_t)Mrows * DFFn * 2);  // 32MB: QKV out | crossQ+KV | FF hidden
    u16* AOb    = (u16*)take(MDbf);
    float* tmpf = (float*)take(MDf);
    float* x1f  = (float*)take(MDf);
    u16*   x1b  = (u16*)take(MDbf);
    float* x2f  = (float*)take(MDf);
    u16*   x2b  = (u16*)take(MDbf);
    if ((size_t)(p - (char*)d_ws) > ws_size) return;  // loud failure instead of corruption

    auto cast = [&](const float* src, u16* dst, size_t n) {
        int n4 = (int)(n / 4);
        cast_bf16_kernel<<<dim3((n4 + 255) / 256), dim3(256), 0, stream>>>(src, dst, n4);
    };
    cast(x, xb, (size_t)Mrows * Dm);
    cast(enc, encb, (size_t)Mrows * Dm);
    cast(sa_wq, wqkv,          DD);
    cast(sa_wk, wqkv + DD,     DD);
    cast(sa_wv, wqkv + 2 * DD, DD);
    cast(sa_wo, wob, DD);
    cast(ca_in_w, cainb, 3 * DD);
    cast(ca_out_w, caoutb, DD);
    cast(ff_w1, fw1b, (size_t)DFFn * Dm);
    cast(ff_w2, fw2b, (size_t)Dm * DFFn);
    hipMemcpyAsync(bias3,          sa_bq, Dm * 4, hipMemcpyDeviceToDevice, stream);
    hipMemcpyAsync(bias3 + Dm,     sa_bk, Dm * 4, hipMemcpyDeviceToDevice, stream);
    hipMemcpyAsync(bias3 + 2 * Dm, sa_bv, Dm * 4, hipMemcpyDeviceToDevice, stream);

    const dim3 blk(256);
    const size_t M4 = (size_t)Mrows * Dm;   // u16 elems in an 8MB slab

    // ---- self-attention block ----
    gemm_bt_kernel<1, 0><<<dim3(3072 / 128, Mrows / 128), blk, 0, stream>>>(xb, wqkv, bias3, (void*)SCR, 3072, Dm);
    attn_kernel<1><<<dim3(Sq / 64, 4 * Hh), blk, 0, stream>>>(SCR, 3072, SCR + 1024, 3072, SCR + 2048, 3072, AOb);
    gemm_bt64_kernel<0, 0><<<dim3(Dm / 128, Mrows / 64), blk, 0, stream>>>(AOb, wob, sa_bo, (void*)tmpf, Dm, Dm);
    add_ln_kernel<<<dim3(Mrows), blk, 0, stream>>>(x, tmpf, n1_g, n1_b, x1f, x1b);

    // ---- cross-attention block ----
    u16* Qc  = SCR;            // [4096][1024]
    u16* KVc = SCR + M4;       // [4096][2048]
    gemm_bt64_kernel<1, 0><<<dim3(Dm / 128, Mrows / 64), blk, 0, stream>>>(x1b, cainb, ca_in_b, (void*)Qc, Dm, Dm);
    gemm_bt_kernel<1, 0><<<dim3(2048 / 128, Mrows / 128), blk, 0, stream>>>(encb, cainb + DD, ca_in_b + Dm, (void*)KVc, 2048, Dm);
    attn_kernel<0><<<dim3(Sq / 64, 4 * Hh), blk, 0, stream>>>(Qc, 1024, KVc, 2048, KVc + 1024, 2048, AOb);
    gemm_bt64_kernel<0, 0><<<dim3(Dm / 128, Mrows / 64), blk, 0, stream>>>(AOb, caoutb, ca_out_b, (void*)tmpf, Dm, Dm);
    add_ln_kernel<<<dim3(Mrows), blk, 0, stream>>>(x1f, tmpf, n2_g, n2_b, x2f, x2b);

    // ---- feed-forward block ----
    u16* ffh = SCR;            // [4096][4096] bf16
    gemm_bt_kernel<1, 1><<<dim3(DFFn / 128, Mrows / 128), blk, 0, stream>>>(x2b, fw1b, ff_b1, (void*)ffh, DFFn, Dm);
    gemm_bt64_kernel<0, 0><<<dim3(Dm / 128, Mrows / 64), blk, 0, stream>>>(ffh, fw2b, ff_b2, (void*)tmpf, Dm, DFFn);
    add_ln_kernel<<<dim3(Mrows), blk, 0, stream>>>(x2f, tmpf, n3_g, n3_b, (float*)d_out, nullptr);
}

// Round 3
// 434.714 us; speedup vs baseline: 1.5178x; 1.0857x over previous
//
#include <hip/hip_runtime.h>
#include <hip/hip_bf16.h>
#include <stdint.h>
#include <math.h>

#define DEV static __device__ __forceinline__

typedef short bf16x8 __attribute__((ext_vector_type(8)));
typedef float f32x4 __attribute__((ext_vector_type(4)));
typedef unsigned short u16;

static constexpr int Sq   = 1024;
static constexpr int Dm   = 1024;
static constexpr int Hh   = 16;
static constexpr int Mrows = 4096; // B*S
static constexpr int DFFn = 4096;

// ---------- helpers ----------

DEV u16 f2bf(float f) {  // fp32 -> bf16 (RNE)
    union { float f; unsigned u; } c; c.f = f;
    unsigned u = c.u;
    return (u16)((u + 0x7FFFu + ((u >> 16) & 1u)) >> 16);
}

DEV void gload_lds16(void* lds, const void* g) {
    using gvp = __attribute__((address_space(1))) void*;
    using lvp = __attribute__((address_space(3))) void*;
    __builtin_amdgcn_global_load_lds((gvp)const_cast<void*>(g), (lvp)lds, 16, 0, 0);
}

// line-pair swizzle for [row][64B-row] LDS tiles: XOR byte bits 4-6 with line index
// (L>>7)&7. Involution; 16B-chunk-granular -> safe for gload_lds pre-swizzled source.
DEV int swz64(int L) { return L ^ (((L >> 7) & 7) << 4); }

// ---------- fp32 -> bf16 cast ----------

__global__ __launch_bounds__(256) void cast_bf16_kernel(
    const float* __restrict__ in, u16* __restrict__ out, int n4)
{
    int i = blockIdx.x * 256 + threadIdx.x;
    if (i >= n4) return;
    float4 v = ((const float4*)in)[i];
    ushort4 o;
    o.x = f2bf(v.x); o.y = f2bf(v.y); o.z = f2bf(v.z); o.w = f2bf(v.w);
    ((ushort4*)out)[i] = o;
}

// ---------- GEMM 256x256, BK=64, 8 waves, 8-phase counted-vmcnt pipeline ----------
// C[M,N] = A[M,K] * W[N,K]^T (+bias). MODE: 1 = bf16 out + bias, 2 = bf16 + bias + relu,
// 3 = f32 partial (split-K via blockIdx.z, no bias).
// LDS: A/B each 2 bufs x 2 K-halves x [256][32 k-elems] (16KB halves), swizzled (T2).
// Staging: 1 half per phase, vmcnt(4) at phases 4/8 only (T4). setprio around MFMA (T5).

template<int MODE>
__global__ __launch_bounds__(512) void gemm256_kernel(
    const u16* __restrict__ A, const u16* __restrict__ W,
    const float* __restrict__ bias, void* __restrict__ Cout,
    float* __restrict__ P1, float* __restrict__ P2, float* __restrict__ P3,
    int N, int ldK, int Kpass)
{
    __shared__ char ldsA[65536];
    __shared__ char ldsB[65536];
    const int tid = threadIdx.x;
    const int w = tid >> 6, l = tid & 63;
    const int lr = l & 15, lg = l >> 4;
    const int wr = w >> 2, wc = w & 3;          // 2 x 4 wave grid; wave tile 128x64
    const size_t tm = (size_t)blockIdx.y * 256;
    const size_t tn = (size_t)blockIdx.x * 256;
    const size_t kz = (size_t)blockIdx.z * Kpass;

    // frag LDS byte offsets within a 16KB half (swizzled)
    int offA[8], offB[4];
    #pragma unroll
    for (int m = 0; m < 8; ++m)
        offA[m] = swz64((wr * 128 + m * 16 + lr) * 64 + lg * 16);
    #pragma unroll
    for (int n = 0; n < 4; ++n)
        offB[n] = swz64((wc * 64 + n * 16 + lr) * 64 + lg * 16);

    // staging source (pre-swizzled global address; LDS dest stays linear)
    const int Ls = swz64(tid * 16);
    const int sr = Ls >> 6, scc = Ls & 63;
    const size_t ldb = (size_t)ldK * 2;          // row stride in bytes
    const char* aS = (const char*)A + (tm + sr) * ldb + kz * 2 + scc;
    const char* bS = (const char*)W + (tn + sr) * ldb + kz * 2 + scc;

    auto AH = [&](int b, int h) -> char* { return ldsA + (b * 2 + h) * 16384; };
    auto BH = [&](int b, int h) -> char* { return ldsB + (b * 2 + h) * 16384; };
    auto stage = [&](char* half, const char* src) {
        gload_lds16(half + w * 1024, src);                    // chunks [0,512)
        gload_lds16(half + 8192 + w * 1024, src + 128 * ldb); // chunks [512,1024) = rows +128
    };

    const int nt = Kpass >> 6;       // K-tiles (even; >= 2)
    const int niter = nt >> 1;

    f32x4 acc[8][4] = {};
    bf16x8 bq[4];

    // prologue: tile0 all 4 halves -> buf0; tile1 k0 halves -> buf1
    stage(AH(0, 0), aS);        stage(BH(0, 0), bS);
    stage(AH(0, 1), aS + 64);   stage(BH(0, 1), bS + 64);
    stage(AH(1, 0), aS + 128);  stage(BH(1, 0), bS + 128);
    asm volatile("s_waitcnt vmcnt(4)" ::: "memory");   // tile0 halves landed
    __builtin_amdgcn_s_barrier();

    for (int it = 0; it < niter; ++it) {
        const int t0 = it * 2;
        const bool last = (it == niter - 1);
        #pragma unroll
        for (int p = 0; p < 8; ++p) {
            const int ts = p >> 2;            // 0: tile t0 (buf0), 1: t0+1 (buf1)
            const int kk = (p >> 1) & 1, mh = p & 1;

            // ds-read this phase's fragments (B reused across mh pair)
            if (mh == 0) {
                #pragma unroll
                for (int n = 0; n < 4; ++n)
                    bq[n] = *(const bf16x8*)(BH(ts, kk) + offB[n]);
            }
            bf16x8 aF[4];
            #pragma unroll
            for (int q = 0; q < 4; ++q)
                aF[q] = *(const bf16x8*)(AH(ts, kk) + offA[mh * 4 + q]);

            // stage one half-tile per phase (schedule derived so every target
            // region's last reader finished >=1 trailing barrier ago)
            if (p == 0)      { stage(AH(1, 1), aS + (size_t)(t0 + 1) * 128 + 64); }
            else if (p == 1) { stage(BH(1, 1), bS + (size_t)(t0 + 1) * 128 + 64); }
            else if (p == 2) { if (t0 + 2 < nt) stage(AH(0, 0), aS + (size_t)(t0 + 2) * 128); }
            else if (p == 3) { if (t0 + 2 < nt) stage(BH(0, 0), bS + (size_t)(t0 + 2) * 128); }
            else if (p == 4) { if (t0 + 2 < nt) stage(AH(0, 1), aS + (size_t)(t0 + 2) * 128 + 64); }
            else if (p == 5) { if (t0 + 2 < nt) stage(BH(0, 1), bS + (size_t)(t0 + 2) * 128 + 64); }
            else if (p == 6) { if (t0 + 3 < nt) stage(AH(1, 0), aS + (size_t)(t0 + 3) * 128); }
            else             { if (t0 + 3 < nt) stage(BH(1, 0), bS + (size_t)(t0 + 3) * 128); }

            // counted-vmcnt checkpoints (T4): oldest 8 of 12 outstanding must land
            if (p == 3) {
                if (last) asm volatile("s_waitcnt vmcnt(0)" ::: "memory"); // drain: fewer in flight in last iter
                else      asm volatile("s_waitcnt vmcnt(4)" ::: "memory");
            } else if (p == 7 && !last) {
                asm volatile("s_waitcnt vmcnt(4)" ::: "memory");
            }
            __builtin_amdgcn_s_barrier();
            asm volatile("s_waitcnt lgkmcnt(0)");
            __builtin_amdgcn_sched_barrier(0);
            __builtin_amdgcn_s_setprio(1);
            #pragma unroll
            for (int q = 0; q < 4; ++q)
                #pragma unroll
                for (int n = 0; n < 4; ++n)
                    acc[mh * 4 + q][n] = __builtin_amdgcn_mfma_f32_16x16x32_bf16(
                        aF[q], bq[n], acc[mh * 4 + q][n], 0, 0, 0);
            __builtin_amdgcn_s_setprio(0);
            __builtin_amdgcn_s_barrier();
        }
    }

    // epilogue
    float* Cp;
    if (MODE == 3) {
        Cp = (blockIdx.z == 0) ? (float*)Cout : (blockIdx.z == 1) ? P1 : (blockIdx.z == 2) ? P2 : P3;
    } else {
        Cp = (float*)Cout;
    }
    float bv[4];
    if (MODE != 3) {
        #pragma unroll
        for (int n = 0; n < 4; ++n) bv[n] = bias[tn + wc * 64 + n * 16 + lr];
    }
    #pragma unroll
    for (int m = 0; m < 8; ++m) {
        #pragma unroll
        for (int n = 0; n < 4; ++n) {
            const size_t col = tn + wc * 64 + n * 16 + lr;
            #pragma unroll
            for (int j = 0; j < 4; ++j) {
                const size_t row = tm + wr * 128 + m * 16 + lg * 4 + j;
                if (MODE == 3) {
                    Cp[row * (size_t)N + col] = acc[m][n][j];
                } else {
                    float v = acc[m][n][j] + bv[n];
                    if (MODE == 2) v = fmaxf(v, 0.f);
                    ((u16*)Cout)[row * (size_t)N + col] = f2bf(v);
                }
            }
        }
    }
}

// ---------- GEMM 64x128 (N=1024 shapes), now with swizzled LDS ----------

template<int OUT_BF16, int RELU>
__global__ __launch_bounds__(256) void gemm_bt64_kernel(
    const u16* __restrict__ A, const u16* __restrict__ W,
    const float* __restrict__ bias, void* __restrict__ Cout,
    int N, int K)
{
    __shared__ char Ald[64 * 64];    // [64 rows][64B], swizzled
    __shared__ char Bld[128 * 64];
    const int tid = threadIdx.x;
    const int w  = tid >> 6, l = tid & 63;
    const int lr = l & 15,  lg = l >> 4;
    const size_t tm = (size_t)blockIdx.y * 64;
    const size_t tn = (size_t)blockIdx.x * 128;

    const int Ls = swz64(tid * 16);
    const int sr = Ls >> 6, scc = Ls & 63;
    const u16* Asrc = A + (tm + sr) * (size_t)K + (scc >> 1);
    const u16* Bsrc = W + (tn + sr) * (size_t)K + (scc >> 1);
    char* AldW = Ald + w * 1024;
    char* BldW = Bld + w * 1024;

    f32x4 acc[4][2] = {};

    for (int k0 = 0; k0 < K; k0 += 32) {
        __syncthreads();
        gload_lds16(AldW,        Asrc + k0);
        gload_lds16(BldW,        Bsrc + k0);
        gload_lds16(BldW + 4096, Bsrc + (size_t)64 * K + k0);
        __syncthreads();

        bf16x8 af[4], bfv[2];
        #pragma unroll
        for (int m = 0; m < 4; ++m)
            af[m] = *(const bf16x8*)(Ald + swz64((m * 16 + lr) * 64 + lg * 16));
        #pragma unroll
        for (int n = 0; n < 2; ++n)
            bfv[n] = *(const bf16x8*)(Bld + swz64((w * 32 + n * 16 + lr) * 64 + lg * 16));
        #pragma unroll
        for (int m = 0; m < 4; ++m)
            #pragma unroll
            for (int n = 0; n < 2; ++n)
                acc[m][n] = __builtin_amdgcn_mfma_f32_16x16x32_bf16(af[m], bfv[n], acc[m][n], 0, 0, 0);
    }

    float bv[2];
    #pragma unroll
    for (int n = 0; n < 2; ++n) bv[n] = bias[tn + w * 32 + n * 16 + lr];

    #pragma unroll
    for (int m = 0; m < 4; ++m) {
        #pragma unroll
        for (int n = 0; n < 2; ++n) {
            const size_t col = tn + w * 32 + n * 16 + lr;
            #pragma unroll
            for (int j = 0; j < 4; ++j) {
                const size_t row = tm + m * 16 + lg * 4 + j;
                float v = acc[m][n][j] + bv[n];
                if (RELU) v = fmaxf(v, 0.f);
                if (OUT_BF16) ((u16*)Cout)[row * (size_t)N + col] = f2bf(v);
                else          ((float*)Cout)[row * (size_t)N + col] = v;
            }
        }
    }
}

// ---------- flash attention, KVBLK=64, XOR-swizzled LDS, double-buffered ----------

template<int CAUSAL>
__global__ __launch_bounds__(256) void attn_kernel(
    const u16* __restrict__ Qm, int ldq,
    const u16* __restrict__ Km, int ldk,
    const u16* __restrict__ Vm, int ldv,
    u16* __restrict__ Om)
{
    __shared__ u16 Kld[2][64 * 64];
    __shared__ u16 Vt [2][64 * 64];
    __shared__ u16 Pld[4][16 * 64];

    const int tid = threadIdx.x;
    const int w = tid >> 6, l = tid & 63;
    const int lr = l & 15, lg = l >> 4;
    const int bh = blockIdx.y;
    const int b = bh >> 4, h = bh & 15;
    const int q0 = blockIdx.x * 64;
    const size_t baseQ = (size_t)b * Sq * ldq + (size_t)h * 64;
    const size_t baseK = (size_t)b * Sq * ldk + (size_t)h * 64;
    const size_t baseV = (size_t)b * Sq * ldv + (size_t)h * 64;
    const size_t baseO = (size_t)b * Sq * Dm  + (size_t)h * 64;

    const int qrow = q0 + w * 16 + lr;
    const bf16x8 aq0 = *(const bf16x8*)&Qm[baseQ + (size_t)qrow * ldq + lg * 8];
    const bf16x8 aq1 = *(const bf16x8*)&Qm[baseQ + (size_t)qrow * ldq + 32 + lg * 8];

    const int kr  = tid >> 2;
    const int kcB = (tid & 3) * 32;
    const int vdg = tid >> 5;
    const int vkp = tid & 31;

    f32x4 o[4] = {};
    float mj[4] = { -INFINITY, -INFINITY, -INFINITY, -INFINITY };
    float lj[4] = {};

    const int kv_end = CAUSAL ? (q0 + 64) : Sq;
    const int nt = kv_end >> 6;

    uint4 ka, kb, va, vb;
    auto loadKV = [&](int kv) {
        ka = *(const uint4*)&Km[baseK + (size_t)(kv + kr) * ldk + kcB / 2];
        kb = *(const uint4*)&Km[baseK + (size_t)(kv + kr) * ldk + kcB / 2 + 8];
        va = *(const uint4*)&Vm[baseV + (size_t)(kv + vkp * 2    ) * ldv + vdg * 8];
        vb = *(const uint4*)&Vm[baseV + (size_t)(kv + vkp * 2 + 1) * ldv + vdg * 8];
    };

    loadKV(0);

    for (int t = 0; t < nt; ++t) {
        const int bsel = t & 1;
        const int kv0 = t << 6;
        {
            char* Kb_ = (char*)Kld[bsel];
            char* Vb_ = (char*)Vt[bsel];
            const int sk = (kr & 7) << 4;
            *(uint4*)(Kb_ + kr * 128 + ((kcB     ) ^ sk)) = ka;
            *(uint4*)(Kb_ + kr * 128 + ((kcB + 16) ^ sk)) = kb;
            const u16* pa_ = (const u16*)&va;
            const u16* pb_ = (const u16*)&vb;
            #pragma unroll
            for (int i = 0; i < 8; ++i) {
                const int d = vdg * 8 + i;
                unsigned val = (unsigned)pa_[i] | ((unsigned)pb_[i] << 16);
                *(unsigned*)(Vb_ + d * 128 + ((vkp * 4) ^ ((d & 7) << 4))) = val;
            }
        }
        __syncthreads();
        if (t + 1 < nt) loadKV((t + 1) << 6);

        const char* Kb_ = (const char*)Kld[bsel];
        const char* Vb_ = (const char*)Vt[bsel];

        f32x4 s[4] = {};
        #pragma unroll
        for (int n = 0; n < 4; ++n) {
            const int row = n * 16 + lr;
            const int sk = (row & 7) << 4;
            bf16x8 kf0 = *(const bf16x8*)(Kb_ + row * 128 + ((     lg * 16) ^ sk));
            bf16x8 kf1 = *(const bf16x8*)(Kb_ + row * 128 + ((64 + lg * 16) ^ sk));
            s[n] = __builtin_amdgcn_mfma_f32_16x16x32_bf16(aq0, kf0, s[n], 0, 0, 0);
            s[n] = __builtin_amdgcn_mfma_f32_16x16x32_bf16(aq1, kf1, s[n], 0, 0, 0);
        }

        float sc[4][4];
        const bool diag = CAUSAL && (kv0 == q0);
        #pragma unroll
        for (int n = 0; n < 4; ++n)
            #pragma unroll
            for (int j = 0; j < 4; ++j) {
                float v = s[n][j] * 0.125f;
                if (diag) {
                    int key = kv0 + n * 16 + lr;
                    int row = q0 + w * 16 + lg * 4 + j;
                    if (key > row) v = -1e9f;
                }
                sc[n][j] = v;
            }

        float scl[4], p[4][4];
        #pragma unroll
        for (int j = 0; j < 4; ++j) {
            float t0 = fmaxf(fmaxf(sc[0][j], sc[1][j]), fmaxf(sc[2][j], sc[3][j]));
            t0 = fmaxf(t0, __shfl_xor(t0, 1));
            t0 = fmaxf(t0, __shfl_xor(t0, 2));
            t0 = fmaxf(t0, __shfl_xor(t0, 4));
            t0 = fmaxf(t0, __shfl_xor(t0, 8));
            float nm = fmaxf(mj[j], t0);
            scl[j] = __expf(mj[j] - nm);
            float rs = 0.f;
            #pragma unroll
            for (int n = 0; n < 4; ++n) { p[n][j] = __expf(sc[n][j] - nm); rs += p[n][j]; }
            rs += __shfl_xor(rs, 1);
            rs += __shfl_xor(rs, 2);
            rs += __shfl_xor(rs, 4);
            rs += __shfl_xor(rs, 8);
            lj[j] = lj[j] * scl[j] + rs;
            mj[j] = nm;
        }
        #pragma unroll
        for (int n2 = 0; n2 < 4; ++n2)
            #pragma unroll
            for (int j = 0; j < 4; ++j) o[n2][j] *= scl[j];

        char* Pw = (char*)Pld[w];
        #pragma unroll
        for (int j = 0; j < 4; ++j) {
            const int prow = lg * 4 + j;
            const int sk = (prow & 7) << 4;
            #pragma unroll
            for (int n = 0; n < 4; ++n)
                *(u16*)(Pw + prow * 128 + (((n * 16 + lr) * 2) ^ sk)) = f2bf(p[n][j]);
        }
        const int skp = (lr & 7) << 4;
        bf16x8 pa0 = *(const bf16x8*)(Pw + lr * 128 + ((     lg * 16) ^ skp));
        bf16x8 pa1 = *(const bf16x8*)(Pw + lr * 128 + ((64 + lg * 16) ^ skp));

        #pragma unroll
        for (int n2 = 0; n2 < 4; ++n2) {
            const int vrow = n2 * 16 + lr;
            const int sk = (vrow & 7) << 4;
            bf16x8 vf0 = *(const bf16x8*)(Vb_ + vrow * 128 + ((     lg * 16) ^ sk));
            bf16x8 vf1 = *(const bf16x8*)(Vb_ + vrow * 128 + ((64 + lg * 16) ^ sk));
            o[n2] = __builtin_amdgcn_mfma_f32_16x16x32_bf16(pa0, vf0, o[n2], 0, 0, 0);
            o[n2] = __builtin_amdgcn_mfma_f32_16x16x32_bf16(pa1, vf1, o[n2], 0, 0, 0);
        }
        __syncthreads();
    }

    #pragma unroll
    for (int n2 = 0; n2 < 4; ++n2)
        #pragma unroll
        for (int j = 0; j < 4; ++j) {
            const size_t row = (size_t)q0 + w * 16 + lg * 4 + j;
            Om[baseO + row * Dm + n2 * 16 + lr] = f2bf(o[n2][j] / lj[j]);
        }
}

// ---------- add + LayerNorm ----------

__global__ __launch_bounds__(256) void add_ln_kernel(
    const float* __restrict__ A, const float* __restrict__ Bv,
    const float* __restrict__ g, const float* __restrict__ be,
    float* __restrict__ Y, u16* __restrict__ Ybf)
{
    const int row = blockIdx.x;
    const int tid = threadIdx.x;
    const size_t off = (size_t)row * Dm;
    float4 a4 = ((const float4*)(A + off))[tid];
    float4 b4 = ((const float4*)(Bv + off))[tid];
    float4 xv;
    xv.x = a4.x + b4.x; xv.y = a4.y + b4.y; xv.z = a4.z + b4.z; xv.w = a4.w + b4.w;
    float s = xv.x + xv.y + xv.z + xv.w;
    float q = xv.x * xv.x + xv.y * xv.y + xv.z * xv.z + xv.w * xv.w;
    #pragma unroll
    for (int m = 1; m < 64; m <<= 1) {
        s += __shfl_xor(s, m);
        q += __shfl_xor(q, m);
    }
    __shared__ float ss[4], qq[4];
    if ((tid & 63) == 0) { ss[tid >> 6] = s; qq[tid >> 6] = q; }
    __syncthreads();
    s = ss[0] + ss[1] + ss[2] + ss[3];
    q = qq[0] + qq[1] + qq[2] + qq[3];
    const float mean = s * (1.f / 1024.f);
    const float var  = q * (1.f / 1024.f) - mean * mean;
    const float rstd = rsqrtf(var + 1e-5f);
    float4 g4  = ((const float4*)g)[tid];
    float4 be4 = ((const float4*)be)[tid];
    float4 y;
    y.x = (xv.x - mean) * rstd * g4.x + be4.x;
    y.y = (xv.y - mean) * rstd * g4.y + be4.y;
    y.z = (xv.z - mean) * rstd * g4.z + be4.z;
    y.w = (xv.w - mean) * rstd * g4.w + be4.w;
    ((float4*)(Y + off))[tid] = y;
    if (Ybf) {
        ushort4 ob;
        ob.x = f2bf(y.x); ob.y = f2bf(y.y); ob.z = f2bf(y.z); ob.w = f2bf(y.w);
        ((ushort4*)(Ybf + off))[tid] = ob;
    }
}

// ---------- 4-partial reduce + bias + add + LayerNorm (ff2 epilogue) ----------

__global__ __launch_bounds__(256) void add_ln_red4_kernel(
    const float* __restrict__ X,
    const float* __restrict__ P0, const float* __restrict__ P1,
    const float* __restrict__ P2, const float* __restrict__ P3,
    const float* __restrict__ bias,
    const float* __restrict__ g, const float* __restrict__ be,
    float* __restrict__ Y)
{
    const int row = blockIdx.x;
    const int tid = threadIdx.x;
    const size_t off = (size_t)row * Dm;
    float4 a4 = ((const float4*)(X + off))[tid];
    float4 q0 = ((const float4*)(P0 + off))[tid];
    float4 q1 = ((const float4*)(P1 + off))[tid];
    float4 q2 = ((const float4*)(P2 + off))[tid];
    float4 q3 = ((const float4*)(P3 + off))[tid];
    float4 b4 = ((const float4*)bias)[tid];
    float4 xv;
    xv.x = a4.x + q0.x + q1.x + q2.x + q3.x + b4.x;
    xv.y = a4.y + q0.y + q1.y + q2.y + q3.y + b4.y;
    xv.z = a4.z + q0.z + q1.z + q2.z + q3.z + b4.z;
    xv.w = a4.w + q0.w + q1.w + q2.w + q3.w + b4.w;
    float s = xv.x + xv.y + xv.z + xv.w;
    float q = xv.x * xv.x + xv.y * xv.y + xv.z * xv.z + xv.w * xv.w;
    #pragma unroll
    for (int m = 1; m < 64; m <<= 1) {
        s += __shfl_xor(s, m);
        q += __shfl_xor(q, m);
    }
    __shared__ float ss[4], qq[4];
    if ((tid & 63) == 0) { ss[tid >> 6] = s; qq[tid >> 6] = q; }
    __syncthreads();
    s = ss[0] + ss[1] + ss[2] + ss[3];
    q = qq[0] + qq[1] + qq[2] + qq[3];
    const float mean = s * (1.f / 1024.f);
    const float var  = q * (1.f / 1024.f) - mean * mean;
    const float rstd = rsqrtf(var + 1e-5f);
    float4 g4  = ((const float4*)g)[tid];
    float4 be4 = ((const float4*)be)[tid];
    float4 y;
    y.x = (xv.x - mean) * rstd * g4.x + be4.x;
    y.y = (xv.y - mean) * rstd * g4.y + be4.y;
    y.z = (xv.z - mean) * rstd * g4.z + be4.z;
    y.w = (xv.w - mean) * rstd * g4.w + be4.w;
    ((float4*)(Y + off))[tid] = y;
}

// ---------- launch ----------

extern "C" void kernel_launch(void* const* d_in, const int* in_sizes, int n_in,
                              void* d_out, int out_size, void* d_ws, size_t ws_size,
                              hipStream_t stream)
{
    const float* x       = (const float*)d_in[0];
    const float* enc     = (const float*)d_in[1];
    const float* sa_wq   = (const float*)d_in[4];
    const float* sa_bq   = (const float*)d_in[5];
    const float* sa_wk   = (const float*)d_in[6];
    const float* sa_bk   = (const float*)d_in[7];
    const float* sa_wv   = (const float*)d_in[8];
    const float* sa_bv   = (const float*)d_in[9];
    const float* sa_wo   = (const float*)d_in[10];
    const float* sa_bo   = (const float*)d_in[11];
    const float* ca_in_w = (const float*)d_in[12];
    const float* ca_in_b = (const float*)d_in[13];
    const float* ca_out_w= (const float*)d_in[14];
    const float* ca_out_b= (const float*)d_in[15];
    const float* ff_w1   = (const float*)d_in[16];
    const float* ff_b1   = (const float*)d_in[17];
    const float* ff_w2   = (const float*)d_in[18];
    const float* ff_b2   = (const float*)d_in[19];
    const float* n1_g = (const float*)d_in[20];
    const float* n1_b = (const float*)d_in[21];
    const float* n2_g = (const float*)d_in[22];
    const float* n2_b = (const float*)d_in[23];
    const float* n3_g = (const float*)d_in[24];
    const float* n3_b = (const float*)d_in[25];

    char* p = (char*)d_ws;
    auto take = [&](size_t bytes) -> char* {
        char* r = p; p += (bytes + 255) & ~(size_t)255; return r;
    };
    const size_t MDbf = (size_t)Mrows * Dm * 2;
    const size_t MDf  = (size_t)Mrows * Dm * 4;
    const size_t DD   = (size_t)Dm * Dm;

    u16* xb     = (u16*)take(MDbf);      // } xb+encb span doubles as ff2 partial 3
    u16* encb   = (u16*)take(MDbf);
    u16* wqkv   = (u16*)take(3 * DD * 2);
    u16* wob    = (u16*)take(DD * 2);
    u16* cainb  = (u16*)take(3 * DD * 2);
    u16* caoutb = (u16*)take(DD * 2);
    u16* fw1b   = (u16*)take((size_t)DFFn * Dm * 2);
    u16* fw2b   = (u16*)take((size_t)Dm * DFFn * 2);
    float* bias3= (float*)take(3 * Dm * 4);
    u16* SCR    = (u16*)take((size_t)Mrows * DFFn * 2);  // 32MB: QKV out | crossQ+KV | FF hidden
    u16* AOb    = (u16*)take(MDbf);      // } AOb+tmpf+x1f+x1b = 48MB contiguous -> ff2 partials 0-2
    float* tmpf = (float*)take(MDf);
    float* x1f  = (float*)take(MDf);
    u16*   x1b  = (u16*)take(MDbf);
    float* x2f  = (float*)take(MDf);
    u16*   x2b  = (u16*)take(MDbf);
    if ((size_t)(p - (char*)d_ws) > ws_size) return;

    // ff2 split-K partials (all dead at ff2 time)
    float* fp0 = (float*)AOb;
    float* fp1 = (float*)((char*)AOb + MDf);
    float* fp2 = (float*)((char*)AOb + 2 * MDf);
    float* fp3 = (float*)xb;

    auto cast = [&](const float* src, u16* dst, size_t n) {
        int n4 = (int)(n / 4);
        cast_bf16_kernel<<<dim3((n4 + 255) / 256), dim3(256), 0, stream>>>(src, dst, n4);
    };
    cast(x, xb, (size_t)Mrows * Dm);
    cast(enc, encb, (size_t)Mrows * Dm);
    cast(sa_wq, wqkv,          DD);
    cast(sa_wk, wqkv + DD,     DD);
    cast(sa_wv, wqkv + 2 * DD, DD);
    cast(sa_wo, wob, DD);
    cast(ca_in_w, cainb, 3 * DD);
    cast(ca_out_w, caoutb, DD);
    cast(ff_w1, fw1b, (size_t)DFFn * Dm);
    cast(ff_w2, fw2b, (size_t)Dm * DFFn);
    hipMemcpyAsync(bias3,          sa_bq, Dm * 4, hipMemcpyDeviceToDevice, stream);
    hipMemcpyAsync(bias3 + Dm,     sa_bk, Dm * 4, hipMemcpyDeviceToDevice, stream);
    hipMemcpyAsync(bias3 + 2 * Dm, sa_bv, Dm * 4, hipMemcpyDeviceToDevice, stream);

    const dim3 blk(256);
    const dim3 blk512(512);
    const size_t M4 = (size_t)Mrows * Dm;

    // ---- self-attention block ----
    gemm256_kernel<1><<<dim3(12, 16), blk512, 0, stream>>>(
        xb, wqkv, bias3, (void*)SCR, nullptr, nullptr, nullptr, 3072, Dm, Dm);
    attn_kernel<1><<<dim3(Sq / 64, 4 * Hh), blk, 0, stream>>>(SCR, 3072, SCR + 1024, 3072, SCR + 2048, 3072, AOb);
    gemm_bt64_kernel<0, 0><<<dim3(Dm / 128, Mrows / 64), blk, 0, stream>>>(AOb, wob, sa_bo, (void*)tmpf, Dm, Dm);
    add_ln_kernel<<<dim3(Mrows), blk, 0, stream>>>(x, tmpf, n1_g, n1_b, x1f, x1b);

    // ---- cross-attention block ----
    u16* Qc  = SCR;
    u16* KVc = SCR + M4;
    gemm_bt64_kernel<1, 0><<<dim3(Dm / 128, Mrows / 64), blk, 0, stream>>>(x1b, cainb, ca_in_b, (void*)Qc, Dm, Dm);
    gemm256_kernel<1><<<dim3(8, 16), blk512, 0, stream>>>(
        encb, cainb + DD, ca_in_b + Dm, (void*)KVc, nullptr, nullptr, nullptr, 2048, Dm, Dm);
    attn_kernel<0><<<dim3(Sq / 64, 4 * Hh), blk, 0, stream>>>(Qc, 1024, KVc, 2048, KVc + 1024, 2048, AOb);
    gemm_bt64_kernel<0, 0><<<dim3(Dm / 128, Mrows / 64), blk, 0, stream>>>(AOb, caoutb, ca_out_b, (void*)tmpf, Dm, Dm);
    add_ln_kernel<<<dim3(Mrows), blk, 0, stream>>>(x1f, tmpf, n2_g, n2_b, x2f, x2b);

    // ---- feed-forward block ----
    u16* ffh = SCR;
    gemm256_kernel<2><<<dim3(16, 16), blk512, 0, stream>>>(
        x2b, fw1b, ff_b1, (void*)ffh, nullptr, nullptr, nullptr, DFFn, Dm, Dm);
    gemm256_kernel<3><<<dim3(4, 16, 4), blk512, 0, stream>>>(
        ffh, fw2b, nullptr, (void*)fp0, fp1, fp2, fp3, Dm, DFFn, 1024);
    add_ln_red4_kernel<<<dim3(Mrows), blk, 0, stream>>>(x2f, fp0, fp1, fp2, fp3, ff_b2, n3_g, n3_b, (float*)d_out);
}

// Round 4
// 402.745 us; speedup vs baseline: 1.6383x; 1.0794x over previous
//
#include <hip/hip_runtime.h>
#include <hip/hip_bf16.h>
#include <stdint.h>
#include <math.h>

#define DEV static __device__ __forceinline__

typedef short bf16x8 __attribute__((ext_vector_type(8)));
typedef float f32x4 __attribute__((ext_vector_type(4)));
typedef unsigned short u16;

static constexpr int Sq   = 1024;
static constexpr int Dm   = 1024;
static constexpr int Hh   = 16;
static constexpr int Mrows = 4096; // B*S
static constexpr int DFFn = 4096;

// ---------- helpers ----------

DEV u16 f2bf(float f) {  // fp32 -> bf16 (RNE)
    union { float f; unsigned u; } c; c.f = f;
    unsigned u = c.u;
    return (u16)((u + 0x7FFFu + ((u >> 16) & 1u)) >> 16);
}

DEV unsigned cvt_pk_bf16(float lo, float hi) {  // D[15:0]=bf16(lo), D[31:16]=bf16(hi)
    unsigned r;
    asm("v_cvt_pk_bf16_f32 %0, %1, %2" : "=v"(r) : "v"(lo), "v"(hi));
    return r;
}

DEV void gload_lds16(void* lds, const void* g) {
    using gvp = __attribute__((address_space(1))) void*;
    using lvp = __attribute__((address_space(3))) void*;
    __builtin_amdgcn_global_load_lds((gvp)const_cast<void*>(g), (lvp)lds, 16, 0, 0);
}

// line-pair swizzle for [row][64B-row] LDS tiles: XOR byte bits 4-6 with line index
// (L>>7)&7. Involution; 16B-chunk-granular -> safe for gload_lds pre-swizzled source.
DEV int swz64(int L) { return L ^ (((L >> 7) & 7) << 4); }

// ---------- fp32 -> bf16 cast ----------

__global__ __launch_bounds__(256) void cast_bf16_kernel(
    const float* __restrict__ in, u16* __restrict__ out, int n4)
{
    int i = blockIdx.x * 256 + threadIdx.x;
    if (i >= n4) return;
    float4 v = ((const float4*)in)[i];
    ushort4 o;
    o.x = f2bf(v.x); o.y = f2bf(v.y); o.z = f2bf(v.z); o.w = f2bf(v.w);
    ((ushort4*)out)[i] = o;
}

// ---------- GEMM 256x256, BK=64, 8 waves, 8-phase counted-vmcnt pipeline ----------

template<int MODE>
__global__ __launch_bounds__(512) void gemm256_kernel(
    const u16* __restrict__ A, const u16* __restrict__ W,
    const float* __restrict__ bias, void* __restrict__ Cout,
    float* __restrict__ P1, float* __restrict__ P2, float* __restrict__ P3,
    int N, int ldK, int Kpass)
{
    __shared__ char ldsA[65536];
    __shared__ char ldsB[65536];
    const int tid = threadIdx.x;
    const int w = tid >> 6, l = tid & 63;
    const int lr = l & 15, lg = l >> 4;
    const int wr = w >> 2, wc = w & 3;
    const size_t tm = (size_t)blockIdx.y * 256;
    const size_t tn = (size_t)blockIdx.x * 256;
    const size_t kz = (size_t)blockIdx.z * Kpass;

    int offA[8], offB[4];
    #pragma unroll
    for (int m = 0; m < 8; ++m)
        offA[m] = swz64((wr * 128 + m * 16 + lr) * 64 + lg * 16);
    #pragma unroll
    for (int n = 0; n < 4; ++n)
        offB[n] = swz64((wc * 64 + n * 16 + lr) * 64 + lg * 16);

    const int Ls = swz64(tid * 16);
    const int sr = Ls >> 6, scc = Ls & 63;
    const size_t ldb = (size_t)ldK * 2;
    const char* aS = (const char*)A + (tm + sr) * ldb + kz * 2 + scc;
    const char* bS = (const char*)W + (tn + sr) * ldb + kz * 2 + scc;

    auto AH = [&](int b, int h) -> char* { return ldsA + (b * 2 + h) * 16384; };
    auto BH = [&](int b, int h) -> char* { return ldsB + (b * 2 + h) * 16384; };
    auto stage = [&](char* half, const char* src) {
        gload_lds16(half + w * 1024, src);
        gload_lds16(half + 8192 + w * 1024, src + 128 * ldb);
    };

    const int nt = Kpass >> 6;
    const int niter = nt >> 1;

    f32x4 acc[8][4] = {};
    bf16x8 bq[4];

    stage(AH(0, 0), aS);        stage(BH(0, 0), bS);
    stage(AH(0, 1), aS + 64);   stage(BH(0, 1), bS + 64);
    stage(AH(1, 0), aS + 128);  stage(BH(1, 0), bS + 128);
    asm volatile("s_waitcnt vmcnt(4)" ::: "memory");
    __builtin_amdgcn_s_barrier();

    for (int it = 0; it < niter; ++it) {
        const int t0 = it * 2;
        const bool last = (it == niter - 1);
        #pragma unroll
        for (int p = 0; p < 8; ++p) {
            const int ts = p >> 2;
            const int kk = (p >> 1) & 1, mh = p & 1;

            if (mh == 0) {
                #pragma unroll
                for (int n = 0; n < 4; ++n)
                    bq[n] = *(const bf16x8*)(BH(ts, kk) + offB[n]);
            }
            bf16x8 aF[4];
            #pragma unroll
            for (int q = 0; q < 4; ++q)
                aF[q] = *(const bf16x8*)(AH(ts, kk) + offA[mh * 4 + q]);

            if (p == 0)      { stage(AH(1, 1), aS + (size_t)(t0 + 1) * 128 + 64); }
            else if (p == 1) { stage(BH(1, 1), bS + (size_t)(t0 + 1) * 128 + 64); }
            else if (p == 2) { if (t0 + 2 < nt) stage(AH(0, 0), aS + (size_t)(t0 + 2) * 128); }
            else if (p == 3) { if (t0 + 2 < nt) stage(BH(0, 0), bS + (size_t)(t0 + 2) * 128); }
            else if (p == 4) { if (t0 + 2 < nt) stage(AH(0, 1), aS + (size_t)(t0 + 2) * 128 + 64); }
            else if (p == 5) { if (t0 + 2 < nt) stage(BH(0, 1), bS + (size_t)(t0 + 2) * 128 + 64); }
            else if (p == 6) { if (t0 + 3 < nt) stage(AH(1, 0), aS + (size_t)(t0 + 3) * 128); }
            else             { if (t0 + 3 < nt) stage(BH(1, 0), bS + (size_t)(t0 + 3) * 128); }

            if (p == 3) {
                if (last) asm volatile("s_waitcnt vmcnt(0)" ::: "memory");
                else      asm volatile("s_waitcnt vmcnt(4)" ::: "memory");
            } else if (p == 7 && !last) {
                asm volatile("s_waitcnt vmcnt(4)" ::: "memory");
            }
            __builtin_amdgcn_s_barrier();
            asm volatile("s_waitcnt lgkmcnt(0)");
            __builtin_amdgcn_sched_barrier(0);
            __builtin_amdgcn_s_setprio(1);
            #pragma unroll
            for (int q = 0; q < 4; ++q)
                #pragma unroll
                for (int n = 0; n < 4; ++n)
                    acc[mh * 4 + q][n] = __builtin_amdgcn_mfma_f32_16x16x32_bf16(
                        aF[q], bq[n], acc[mh * 4 + q][n], 0, 0, 0);
            __builtin_amdgcn_s_setprio(0);
            __builtin_amdgcn_s_barrier();
        }
    }

    float* Cp;
    if (MODE == 3) {
        Cp = (blockIdx.z == 0) ? (float*)Cout : (blockIdx.z == 1) ? P1 : (blockIdx.z == 2) ? P2 : P3;
    } else {
        Cp = (float*)Cout;
    }
    float bv[4];
    if (MODE != 3) {
        #pragma unroll
        for (int n = 0; n < 4; ++n) bv[n] = bias[tn + wc * 64 + n * 16 + lr];
    }
    #pragma unroll
    for (int m = 0; m < 8; ++m) {
        #pragma unroll
        for (int n = 0; n < 4; ++n) {
            const size_t col = tn + wc * 64 + n * 16 + lr;
            #pragma unroll
            for (int j = 0; j < 4; ++j) {
                const size_t row = tm + wr * 128 + m * 16 + lg * 4 + j;
                if (MODE == 3) {
                    Cp[row * (size_t)N + col] = acc[m][n][j];
                } else {
                    float v = acc[m][n][j] + bv[n];
                    if (MODE == 2) v = fmaxf(v, 0.f);
                    ((u16*)Cout)[row * (size_t)N + col] = f2bf(v);
                }
            }
        }
    }
}

// ---------- GEMM 64x128 (N=1024 shapes), swizzled LDS ----------

template<int OUT_BF16, int RELU>
__global__ __launch_bounds__(256) void gemm_bt64_kernel(
    const u16* __restrict__ A, const u16* __restrict__ W,
    const float* __restrict__ bias, void* __restrict__ Cout,
    int N, int K)
{
    __shared__ char Ald[64 * 64];
    __shared__ char Bld[128 * 64];
    const int tid = threadIdx.x;
    const int w  = tid >> 6, l = tid & 63;
    const int lr = l & 15,  lg = l >> 4;
    const size_t tm = (size_t)blockIdx.y * 64;
    const size_t tn = (size_t)blockIdx.x * 128;

    const int Ls = swz64(tid * 16);
    const int sr = Ls >> 6, scc = Ls & 63;
    const u16* Asrc = A + (tm + sr) * (size_t)K + (scc >> 1);
    const u16* Bsrc = W + (tn + sr) * (size_t)K + (scc >> 1);
    char* AldW = Ald + w * 1024;
    char* BldW = Bld + w * 1024;

    f32x4 acc[4][2] = {};

    for (int k0 = 0; k0 < K; k0 += 32) {
        __syncthreads();
        gload_lds16(AldW,        Asrc + k0);
        gload_lds16(BldW,        Bsrc + k0);
        gload_lds16(BldW + 4096, Bsrc + (size_t)64 * K + k0);
        __syncthreads();

        bf16x8 af[4], bfv[2];
        #pragma unroll
        for (int m = 0; m < 4; ++m)
            af[m] = *(const bf16x8*)(Ald + swz64((m * 16 + lr) * 64 + lg * 16));
        #pragma unroll
        for (int n = 0; n < 2; ++n)
            bfv[n] = *(const bf16x8*)(Bld + swz64((w * 32 + n * 16 + lr) * 64 + lg * 16));
        #pragma unroll
        for (int m = 0; m < 4; ++m)
            #pragma unroll
            for (int n = 0; n < 2; ++n)
                acc[m][n] = __builtin_amdgcn_mfma_f32_16x16x32_bf16(af[m], bfv[n], acc[m][n], 0, 0, 0);
    }

    float bv[2];
    #pragma unroll
    for (int n = 0; n < 2; ++n) bv[n] = bias[tn + w * 32 + n * 16 + lr];

    #pragma unroll
    for (int m = 0; m < 4; ++m) {
        #pragma unroll
        for (int n = 0; n < 2; ++n) {
            const size_t col = tn + w * 32 + n * 16 + lr;
            #pragma unroll
            for (int j = 0; j < 4; ++j) {
                const size_t row = tm + m * 16 + lg * 4 + j;
                float v = acc[m][n][j] + bv[n];
                if (RELU) v = fmaxf(v, 0.f);
                if (OUT_BF16) ((u16*)Cout)[row * (size_t)N + col] = f2bf(v);
                else          ((float*)Cout)[row * (size_t)N + col] = v;
            }
        }
    }
}

// ---------- flash attention: swapped QK^T, in-register softmax ----------
// grid: (S/64, B*H); 4 waves; wave w owns q-rows q0+w*16..+15 (q = lane&15).
// QK^T computed as mfma(K,Q) so each lane holds 16 scores of one q-row:
// s[n][j] = score(key = kv0+n*16+lg*4+j, q = q0+w*16+lr). Softmax reduce is
// in-lane tree + shfl_xor(16,32). P redistributed to PV A-frag layout
// (k = lg*8+i) via cvt_pk + 16 ds_bpermute. No P LDS tile (32KB total).

template<int CAUSAL>
__global__ __launch_bounds__(256, 4) void attn_kernel(
    const u16* __restrict__ Qm, int ldq,
    const u16* __restrict__ Km, int ldk,
    const u16* __restrict__ Vm, int ldv,
    u16* __restrict__ Om)
{
    __shared__ u16 Kld[2][64 * 64];
    __shared__ u16 Vt [2][64 * 64];

    const int tid = threadIdx.x;
    const int w = tid >> 6, l = tid & 63;
    const int lr = l & 15, lg = l >> 4;
    const int bh = blockIdx.y;
    const int b = bh >> 4, h = bh & 15;
    const int q0 = blockIdx.x * 64;
    const size_t baseQ = (size_t)b * Sq * ldq + (size_t)h * 64;
    const size_t baseK = (size_t)b * Sq * ldk + (size_t)h * 64;
    const size_t baseV = (size_t)b * Sq * ldv + (size_t)h * 64;
    const size_t baseO = (size_t)b * Sq * Dm  + (size_t)h * 64;

    // Q fragment (B-operand in swapped form: col=lane&15 -> q, k=(lane>>4)*8+i)
    const int qrow = q0 + w * 16 + lr;
    const bf16x8 bq0 = *(const bf16x8*)&Qm[baseQ + (size_t)qrow * ldq + lg * 8];
    const bf16x8 bq1 = *(const bf16x8*)&Qm[baseQ + (size_t)qrow * ldq + 32 + lg * 8];

    const int kr  = tid >> 2;
    const int kcB = (tid & 3) * 32;
    const int vdg = tid >> 5;
    const int vkp = tid & 31;

    // P-redistribution shfl sources: target word m of k-half kh comes from
    // lane (lg_s = (lg&1)*2 + (m>>1), q=lr), word (2*kh + (lg>>1))*2 + (m&1)
    const int srcA = lr + ((lg & 1) << 5);
    const int srcB = srcA + 16;
    const bool hiSel = (lg >> 1) & 1;

    f32x4 o[4] = {};
    float mj = -INFINITY;   // running max (log2 units), q-row = lr
    float lj = 0.f;

    const int kv_end = CAUSAL ? (q0 + 64) : Sq;
    const int nt = kv_end >> 6;
    const float cexp = 0.125f * 1.44269504f;   // 1/sqrt(64) * log2(e)

    uint4 ka, kb, va, vb;
    auto loadKV = [&](int kv) {
        ka = *(const uint4*)&Km[baseK + (size_t)(kv + kr) * ldk + kcB / 2];
        kb = *(const uint4*)&Km[baseK + (size_t)(kv + kr) * ldk + kcB / 2 + 8];
        va = *(const uint4*)&Vm[baseV + (size_t)(kv + vkp * 2    ) * ldv + vdg * 8];
        vb = *(const uint4*)&Vm[baseV + (size_t)(kv + vkp * 2 + 1) * ldv + vdg * 8];
    };

    loadKV(0);

    for (int t = 0; t < nt; ++t) {
        const int bsel = t & 1;
        const int kv0 = t << 6;
        {
            char* Kb_ = (char*)Kld[bsel];
            char* Vb_ = (char*)Vt[bsel];
            const int sk = (kr & 7) << 4;
            *(uint4*)(Kb_ + kr * 128 + ((kcB     ) ^ sk)) = ka;
            *(uint4*)(Kb_ + kr * 128 + ((kcB + 16) ^ sk)) = kb;
            const u16* pa_ = (const u16*)&va;
            const u16* pb_ = (const u16*)&vb;
            #pragma unroll
            for (int i = 0; i < 8; ++i) {
                const int d = vdg * 8 + i;
                unsigned val = (unsigned)pa_[i] | ((unsigned)pb_[i] << 16);
                *(unsigned*)(Vb_ + d * 128 + ((vkp * 4) ^ ((d & 7) << 4))) = val;
            }
        }
        __syncthreads();
        if (t + 1 < nt) loadKV((t + 1) << 6);

        const char* Kb_ = (const char*)Kld[bsel];
        const char* Vb_ = (const char*)Vt[bsel];

        // QK^T swapped: s[n] = K_tile(n) x Q -> row=key-sub, col=q
        f32x4 s[4] = {};
        #pragma unroll
        for (int n = 0; n < 4; ++n) {
            const int row = n * 16 + lr;
            const int sk = (row & 7) << 4;
            bf16x8 kf0 = *(const bf16x8*)(Kb_ + row * 128 + ((     lg * 16) ^ sk));
            bf16x8 kf1 = *(const bf16x8*)(Kb_ + row * 128 + ((64 + lg * 16) ^ sk));
            s[n] = __builtin_amdgcn_mfma_f32_16x16x32_bf16(kf0, bq0, s[n], 0, 0, 0);
            s[n] = __builtin_amdgcn_mfma_f32_16x16x32_bf16(kf1, bq1, s[n], 0, 0, 0);
        }

        float sc[4][4];
        const bool diag = CAUSAL && (kv0 == q0);
        #pragma unroll
        for (int n = 0; n < 4; ++n)
            #pragma unroll
            for (int j = 0; j < 4; ++j) {
                float v = s[n][j] * cexp;
                if (diag) {
                    int key = kv0 + n * 16 + lg * 4 + j;
                    if (key > qrow) v = -3.0e8f;
                }
                sc[n][j] = v;
            }

        // in-lane max tree over 16, then cross-lg
        float t4[4];
        #pragma unroll
        for (int n = 0; n < 4; ++n)
            t4[n] = fmaxf(fmaxf(sc[n][0], sc[n][1]), fmaxf(sc[n][2], sc[n][3]));
        float tmax = fmaxf(fmaxf(t4[0], t4[1]), fmaxf(t4[2], t4[3]));
        tmax = fmaxf(tmax, __shfl_xor(tmax, 16));
        tmax = fmaxf(tmax, __shfl_xor(tmax, 32));

        const bool noresc = __all(tmax <= mj);
        const float nm = noresc ? mj : fmaxf(mj, tmax);

        float p[4][4];
        float r4[4];
        #pragma unroll
        for (int n = 0; n < 4; ++n) {
            #pragma unroll
            for (int j = 0; j < 4; ++j) p[n][j] = exp2f(sc[n][j] - nm);
            r4[n] = (p[n][0] + p[n][1]) + (p[n][2] + p[n][3]);
        }
        float rs = (r4[0] + r4[1]) + (r4[2] + r4[3]);
        rs += __shfl_xor(rs, 16);
        rs += __shfl_xor(rs, 32);

        if (noresc) {
            lj += rs;
        } else {
            const float scl = exp2f(mj - nm);
            lj = lj * scl + rs;
            mj = nm;
            float sclr[4];
            #pragma unroll
            for (int j = 0; j < 4; ++j) sclr[j] = __shfl(scl, lg * 4 + j);
            #pragma unroll
            for (int n2 = 0; n2 < 4; ++n2)
                #pragma unroll
                for (int j = 0; j < 4; ++j) o[n2][j] *= sclr[j];
        }

        // pack P to bf16 words: wd[n*2+h] covers keys n*16+lg*4+2h, +1
        unsigned wd[8];
        #pragma unroll
        for (int n = 0; n < 4; ++n) {
            wd[n * 2]     = cvt_pk_bf16(p[n][0], p[n][1]);
            wd[n * 2 + 1] = cvt_pk_bf16(p[n][2], p[n][3]);
        }
        // redistribute to A-frag layout (k = lg*8+i per k-half)
        union { unsigned u[4]; bf16x8 v; } pu0, pu1;
        #pragma unroll
        for (int m = 0; m < 4; ++m) {
            const int src = (m & 2) ? srcB : srcA;
            int a0 = __shfl((int)wd[(m & 1)],     src);
            int a1 = __shfl((int)wd[2 + (m & 1)], src);
            pu0.u[m] = hiSel ? (unsigned)a1 : (unsigned)a0;
            int b0 = __shfl((int)wd[4 + (m & 1)], src);
            int b1 = __shfl((int)wd[6 + (m & 1)], src);
            pu1.u[m] = hiSel ? (unsigned)b1 : (unsigned)b0;
        }

        #pragma unroll
        for (int n2 = 0; n2 < 4; ++n2) {
            const int vrow = n2 * 16 + lr;
            const int sk = (vrow & 7) << 4;
            bf16x8 vf0 = *(const bf16x8*)(Vb_ + vrow * 128 + ((     lg * 16) ^ sk));
            bf16x8 vf1 = *(const bf16x8*)(Vb_ + vrow * 128 + ((64 + lg * 16) ^ sk));
            o[n2] = __builtin_amdgcn_mfma_f32_16x16x32_bf16(pu0.v, vf0, o[n2], 0, 0, 0);
            o[n2] = __builtin_amdgcn_mfma_f32_16x16x32_bf16(pu1.v, vf1, o[n2], 0, 0, 0);
        }
        __syncthreads();
    }

    // final: divide rows by lj (held per q=lr lanes; output rows q'=lg*4+j)
    float ljr[4];
    #pragma unroll
    for (int j = 0; j < 4; ++j)
        ljr[j] = __builtin_amdgcn_rcpf(__shfl(lj, lg * 4 + j));
    #pragma unroll
    for (int n2 = 0; n2 < 4; ++n2)
        #pragma unroll
        for (int j = 0; j < 4; ++j) {
            const size_t row = (size_t)q0 + w * 16 + lg * 4 + j;
            Om[baseO + row * Dm + n2 * 16 + lr] = f2bf(o[n2][j] * ljr[j]);
        }
}

// ---------- add + LayerNorm ----------

__global__ __launch_bounds__(256) void add_ln_kernel(
    const float* __restrict__ A, const float* __restrict__ Bv,
    const float* __restrict__ g, const float* __restrict__ be,
    float* __restrict__ Y, u16* __restrict__ Ybf)
{
    const int row = blockIdx.x;
    const int tid = threadIdx.x;
    const size_t off = (size_t)row * Dm;
    float4 a4 = ((const float4*)(A + off))[tid];
    float4 b4 = ((const float4*)(Bv + off))[tid];
    float4 xv;
    xv.x = a4.x + b4.x; xv.y = a4.y + b4.y; xv.z = a4.z + b4.z; xv.w = a4.w + b4.w;
    float s = xv.x + xv.y + xv.z + xv.w;
    float q = xv.x * xv.x + xv.y * xv.y + xv.z * xv.z + xv.w * xv.w;
    #pragma unroll
    for (int m = 1; m < 64; m <<= 1) {
        s += __shfl_xor(s, m);
        q += __shfl_xor(q, m);
    }
    __shared__ float ss[4], qq[4];
    if ((tid & 63) == 0) { ss[tid >> 6] = s; qq[tid >> 6] = q; }
    __syncthreads();
    s = ss[0] + ss[1] + ss[2] + ss[3];
    q = qq[0] + qq[1] + qq[2] + qq[3];
    const float mean = s * (1.f / 1024.f);
    const float var  = q * (1.f / 1024.f) - mean * mean;
    const float rstd = rsqrtf(var + 1e-5f);
    float4 g4  = ((const float4*)g)[tid];
    float4 be4 = ((const float4*)be)[tid];
    float4 y;
    y.x = (xv.x - mean) * rstd * g4.x + be4.x;
    y.y = (xv.y - mean) * rstd * g4.y + be4.y;
    y.z = (xv.z - mean) * rstd * g4.z + be4.z;
    y.w = (xv.w - mean) * rstd * g4.w + be4.w;
    ((float4*)(Y + off))[tid] = y;
    if (Ybf) {
        ushort4 ob;
        ob.x = f2bf(y.x); ob.y = f2bf(y.y); ob.z = f2bf(y.z); ob.w = f2bf(y.w);
        ((ushort4*)(Ybf + off))[tid] = ob;
    }
}

// ---------- 4-partial reduce + bias + add + LayerNorm (ff2 epilogue) ----------

__global__ __launch_bounds__(256) void add_ln_red4_kernel(
    const float* __restrict__ X,
    const float* __restrict__ P0, const float* __restrict__ P1,
    const float* __restrict__ P2, const float* __restrict__ P3,
    const float* __restrict__ bias,
    const float* __restrict__ g, const float* __restrict__ be,
    float* __restrict__ Y)
{
    const int row = blockIdx.x;
    const int tid = threadIdx.x;
    const size_t off = (size_t)row * Dm;
    float4 a4 = ((const float4*)(X + off))[tid];
    float4 q0 = ((const float4*)(P0 + off))[tid];
    float4 q1 = ((const float4*)(P1 + off))[tid];
    float4 q2 = ((const float4*)(P2 + off))[tid];
    float4 q3 = ((const float4*)(P3 + off))[tid];
    float4 b4 = ((const float4*)bias)[tid];
    float4 xv;
    xv.x = a4.x + q0.x + q1.x + q2.x + q3.x + b4.x;
    xv.y = a4.y + q0.y + q1.y + q2.y + q3.y + b4.y;
    xv.z = a4.z + q0.z + q1.z + q2.z + q3.z + b4.z;
    xv.w = a4.w + q0.w + q1.w + q2.w + q3.w + b4.w;
    float s = xv.x + xv.y + xv.z + xv.w;
    float q = xv.x * xv.x + xv.y * xv.y + xv.z * xv.z + xv.w * xv.w;
    #pragma unroll
    for (int m = 1; m < 64; m <<= 1) {
        s += __shfl_xor(s, m);
        q += __shfl_xor(q, m);
    }
    __shared__ float ss[4], qq[4];
    if ((tid & 63) == 0) { ss[tid >> 6] = s; qq[tid >> 6] = q; }
    __syncthreads();
    s = ss[0] + ss[1] + ss[2] + ss[3];
    q = qq[0] + qq[1] + qq[2] + qq[3];
    const float mean = s * (1.f / 1024.f);
    const float var  = q * (1.f / 1024.f) - mean * mean;
    const float rstd = rsqrtf(var + 1e-5f);
    float4 g4  = ((const float4*)g)[tid];
    float4 be4 = ((const float4*)be)[tid];
    float4 y;
    y.x = (xv.x - mean) * rstd * g4.x + be4.x;
    y.y = (xv.y - mean) * rstd * g4.y + be4.y;
    y.z = (xv.z - mean) * rstd * g4.z + be4.z;
    y.w = (xv.w - mean) * rstd * g4.w + be4.w;
    ((float4*)(Y + off))[tid] = y;
}

// ---------- launch ----------

extern "C" void kernel_launch(void* const* d_in, const int* in_sizes, int n_in,
                              void* d_out, int out_size, void* d_ws, size_t ws_size,
                              hipStream_t stream)
{
    const float* x       = (const float*)d_in[0];
    const float* enc     = (const float*)d_in[1];
    const float* sa_wq   = (const float*)d_in[4];
    const float* sa_bq   = (const float*)d_in[5];
    const float* sa_wk   = (const float*)d_in[6];
    const float* sa_bk   = (const float*)d_in[7];
    const float* sa_wv   = (const float*)d_in[8];
    const float* sa_bv   = (const float*)d_in[9];
    const float* sa_wo   = (const float*)d_in[10];
    const float* sa_bo   = (const float*)d_in[11];
    const float* ca_in_w = (const float*)d_in[12];
    const float* ca_in_b = (const float*)d_in[13];
    const float* ca_out_w= (const float*)d_in[14];
    const float* ca_out_b= (const float*)d_in[15];
    const float* ff_w1   = (const float*)d_in[16];
    const float* ff_b1   = (const float*)d_in[17];
    const float* ff_w2   = (const float*)d_in[18];
    const float* ff_b2   = (const float*)d_in[19];
    const float* n1_g = (const float*)d_in[20];
    const float* n1_b = (const float*)d_in[21];
    const float* n2_g = (const float*)d_in[22];
    const float* n2_b = (const float*)d_in[23];
    const float* n3_g = (const float*)d_in[24];
    const float* n3_b = (const float*)d_in[25];

    char* p = (char*)d_ws;
    auto take = [&](size_t bytes) -> char* {
        char* r = p; p += (bytes + 255) & ~(size_t)255; return r;
    };
    const size_t MDbf = (size_t)Mrows * Dm * 2;
    const size_t MDf  = (size_t)Mrows * Dm * 4;
    const size_t DD   = (size_t)Dm * Dm;

    u16* xb     = (u16*)take(MDbf);
    u16* encb   = (u16*)take(MDbf);
    u16* wqkv   = (u16*)take(3 * DD * 2);
    u16* wob    = (u16*)take(DD * 2);
    u16* cainb  = (u16*)take(3 * DD * 2);
    u16* caoutb = (u16*)take(DD * 2);
    u16* fw1b   = (u16*)take((size_t)DFFn * Dm * 2);
    u16* fw2b   = (u16*)take((size_t)Dm * DFFn * 2);
    float* bias3= (float*)take(3 * Dm * 4);
    u16* SCR    = (u16*)take((size_t)Mrows * DFFn * 2);
    u16* AOb    = (u16*)take(MDbf);
    float* tmpf = (float*)take(MDf);
    float* x1f  = (float*)take(MDf);
    u16*   x1b  = (u16*)take(MDbf);
    float* x2f  = (float*)take(MDf);
    u16*   x2b  = (u16*)take(MDbf);
    if ((size_t)(p - (char*)d_ws) > ws_size) return;

    float* fp0 = (float*)AOb;
    float* fp1 = (float*)((char*)AOb + MDf);
    float* fp2 = (float*)((char*)AOb + 2 * MDf);
    float* fp3 = (float*)xb;

    auto cast = [&](const float* src, u16* dst, size_t n) {
        int n4 = (int)(n / 4);
        cast_bf16_kernel<<<dim3((n4 + 255) / 256), dim3(256), 0, stream>>>(src, dst, n4);
    };
    cast(x, xb, (size_t)Mrows * Dm);
    cast(enc, encb, (size_t)Mrows * Dm);
    cast(sa_wq, wqkv,          DD);
    cast(sa_wk, wqkv + DD,     DD);
    cast(sa_wv, wqkv + 2 * DD, DD);
    cast(sa_wo, wob, DD);
    cast(ca_in_w, cainb, 3 * DD);
    cast(ca_out_w, caoutb, DD);
    cast(ff_w1, fw1b, (size_t)DFFn * Dm);
    cast(ff_w2, fw2b, (size_t)Dm * DFFn);
    hipMemcpyAsync(bias3,          sa_bq, Dm * 4, hipMemcpyDeviceToDevice, stream);
    hipMemcpyAsync(bias3 + Dm,     sa_bk, Dm * 4, hipMemcpyDeviceToDevice, stream);
    hipMemcpyAsync(bias3 + 2 * Dm, sa_bv, Dm * 4, hipMemcpyDeviceToDevice, stream);

    const dim3 blk(256);
    const dim3 blk512(512);
    const size_t M4 = (size_t)Mrows * Dm;

    // ---- self-attention block ----
    gemm256_kernel<1><<<dim3(12, 16), blk512, 0, stream>>>(
        xb, wqkv, bias3, (void*)SCR, nullptr, nullptr, nullptr, 3072, Dm, Dm);
    attn_kernel<1><<<dim3(Sq / 64, 4 * Hh), blk, 0, stream>>>(SCR, 3072, SCR + 1024, 3072, SCR + 2048, 3072, AOb);
    gemm_bt64_kernel<0, 0><<<dim3(Dm / 128, Mrows / 64), blk, 0, stream>>>(AOb, wob, sa_bo, (void*)tmpf, Dm, Dm);
    add_ln_kernel<<<dim3(Mrows), blk, 0, stream>>>(x, tmpf, n1_g, n1_b, x1f, x1b);

    // ---- cross-attention block ----
    u16* Qc  = SCR;
    u16* KVc = SCR + M4;
    gemm_bt64_kernel<1, 0><<<dim3(Dm / 128, Mrows / 64), blk, 0, stream>>>(x1b, cainb, ca_in_b, (void*)Qc, Dm, Dm);
    gemm256_kernel<1><<<dim3(8, 16), blk512, 0, stream>>>(
        encb, cainb + DD, ca_in_b + Dm, (void*)KVc, nullptr, nullptr, nullptr, 2048, Dm, Dm);
    attn_kernel<0><<<dim3(Sq / 64, 4 * Hh), blk, 0, stream>>>(Qc, 1024, KVc, 2048, KVc + 1024, 2048, AOb);
    gemm_bt64_kernel<0, 0><<<dim3(Dm / 128, Mrows / 64), blk, 0, stream>>>(AOb, caoutb, ca_out_b, (void*)tmpf, Dm, Dm);
    add_ln_kernel<<<dim3(Mrows), blk, 0, stream>>>(x1f, tmpf, n2_g, n2_b, x2f, x2b);

    // ---- feed-forward block ----
    u16* ffh = SCR;
    gemm256_kernel<2><<<dim3(16, 16), blk512, 0, stream>>>(
        x2b, fw1b, ff_b1, (void*)ffh, nullptr, nullptr, nullptr, DFFn, Dm, Dm);
    gemm256_kernel<3><<<dim3(4, 16, 4), blk512, 0, stream>>>(
        ffh, fw2b, nullptr, (void*)fp0, fp1, fp2, fp3, Dm, DFFn, 1024);
    add_ln_red4_kernel<<<dim3(Mrows), blk, 0, stream>>>(x2f, fp0, fp1, fp2, fp3, ff_b2, n3_g, n3_b, (float*)d_out);
}